// Round 1
// baseline (411.856 us; speedup 1.0000x reference)
//
#include <hip/hip_runtime.h>
#include <hip/hip_bf16.h>

// Non-local block, B=8 C=512 H=W=64, IC=256, N2=HW=4096, N=2048 (folded).
//
// Round-6: convtr v3 — full-C tile (64px x 512c), contiguous 64KB block
// writes, in-register 4x8 transpose (b128 LDS ops, conflict-free), XCD-slab
// ordering so concurrent blocks on an XCD read adjacent chunks of the same
// DRAM rows. Rest identical to round 5.

typedef __attribute__((ext_vector_type(8))) short short8;
typedef __attribute__((ext_vector_type(4))) short short4v;
typedef __attribute__((ext_vector_type(4))) float f32x4;

enum { EPI_BF16 = 0, EPI_BF16_BIAS = 1 };

__device__ __forceinline__ short f2bf(float f) {
  union { __hip_bfloat16 h; short s; } u; u.h = __float2bfloat16(f); return u.s;
}
__device__ __forceinline__ float bf2f(short s) {
  union { short s; __hip_bfloat16 h; } u; u.s = s; return __bfloat162float(u.h);
}

__device__ __forceinline__ void async_ld16(const void* g, void* l) {
  __builtin_amdgcn_global_load_lds(
      (const __attribute__((address_space(1))) unsigned int*)(unsigned long long)g,
      (__attribute__((address_space(3))) unsigned int*)(unsigned int)(unsigned long long)l,
      16, 0, 0);
}

// ---------------- 8-wave 128x128 GEMM: C[i][j] = sum_k A[i][k]*BT[j][k] ----
template<int EPI>
__global__ __launch_bounds__(512, 4)
void gemm8(const short* __restrict__ Ag, long sA, int lda,
           const short* __restrict__ Bg, long sB, int ldb,
           short* __restrict__ Cg, long sC, int ldc,
           int K, const float* __restrict__ bias)
{
  __shared__ __align__(16) short As[128 * 32];
  __shared__ __align__(16) short Bs[128 * 32];
  const int bz = blockIdx.z;
  const short* A = Ag + (long)bz * sA;
  const short* B = Bg + (long)bz * sB;
  const int m0 = blockIdx.y * 128;
  const int n0 = blockIdx.x * 128;
  const int t = threadIdx.x;
  const int wv = t >> 6, ln = t & 63;
  const int wr = wv >> 1, wc = wv & 1;
  const int fr = ln & 15, q8 = (ln >> 4) * 8;
  const int rowA = t >> 2, kc = (t & 3) * 8;

  f32x4 acc[2][4];
  #pragma unroll
  for (int i = 0; i < 2; i++)
    #pragma unroll
    for (int j = 0; j < 4; j++)
      #pragma unroll
      for (int r = 0; r < 4; r++) acc[i][j][r] = 0.f;

  for (int kk = 0; kk < K; kk += 32) {
    async_ld16(A + (long)(m0 + rowA) * lda + kk + kc, As + wv * 512);
    async_ld16(B + (long)(n0 + rowA) * ldb + kk + kc, Bs + wv * 512);
    __syncthreads();
    short8 af[2], bfr[4];
    #pragma unroll
    for (int mi = 0; mi < 2; mi++) af[mi] = *(const short8*)&As[(wr * 32 + mi * 16 + fr) * 32 + q8];
    #pragma unroll
    for (int ni = 0; ni < 4; ni++) bfr[ni] = *(const short8*)&Bs[(wc * 64 + ni * 16 + fr) * 32 + q8];
    #pragma unroll
    for (int mi = 0; mi < 2; mi++)
      #pragma unroll
      for (int ni = 0; ni < 4; ni++)
        acc[mi][ni] = __builtin_amdgcn_mfma_f32_16x16x32_bf16(af[mi], bfr[ni], acc[mi][ni], 0, 0, 0);
    __syncthreads();
  }

  const int colb = n0 + wc * 64 + fr;
  const int rowb = m0 + wr * 32 + (ln >> 4) * 4;
  #pragma unroll
  for (int mi = 0; mi < 2; mi++)
    #pragma unroll
    for (int r = 0; r < 4; r++) {
      const int mr = rowb + mi * 16 + r;
      float badd = 0.f;
      if constexpr (EPI == EPI_BF16_BIAS) badd = bias[mr];
      #pragma unroll
      for (int ni = 0; ni < 4; ni++)
        Cg[(long)bz * sC + (long)mr * ldc + colb + ni * 16] = f2bf(acc[mi][ni][r] + badd);
    }
}

// ---------------- OV GEMM with XCD-locality swizzle ------------------------
// OVT[b][n][c] = sum_m E[n][m]*G''[c][m]. 512 blocks; all 4 c-blocks of one
// (b,n) E-slab land on the same XCD (launch id === slab mod 8) so the 512KB
// slab is served from that XCD's L2 after the first pull.
__global__ __launch_bounds__(512, 4)
void ov_k(const short* __restrict__ Eg, const short* __restrict__ Gg,
          short* __restrict__ Cg)
{
  const int L = blockIdx.x;
  const int xcd = L & 7, k = L >> 3;
  const int slab = xcd + ((k >> 2) << 3);   // 0..127
  const int bz = slab >> 4, by = slab & 15, bx = k & 3;

  __shared__ __align__(16) short As[128 * 32];
  __shared__ __align__(16) short Bs[128 * 32];
  const short* A = Eg + ((long)bz << 22);
  const short* B = Gg + ((long)bz << 20);
  const int m0 = by * 128;
  const int n0 = bx * 128;
  const int t = threadIdx.x;
  const int wv = t >> 6, ln = t & 63;
  const int wr = wv >> 1, wc = wv & 1;
  const int fr = ln & 15, q8 = (ln >> 4) * 8;
  const int rowA = t >> 2, kc = (t & 3) * 8;

  f32x4 acc[2][4];
  #pragma unroll
  for (int i = 0; i < 2; i++)
    #pragma unroll
    for (int j = 0; j < 4; j++)
      #pragma unroll
      for (int r = 0; r < 4; r++) acc[i][j][r] = 0.f;

  for (int kk = 0; kk < 2048; kk += 32) {
    async_ld16(A + (long)(m0 + rowA) * 2048 + kk + kc, As + wv * 512);
    async_ld16(B + (long)(n0 + rowA) * 2048 + kk + kc, Bs + wv * 512);
    __syncthreads();
    short8 af[2], bfr[4];
    #pragma unroll
    for (int mi = 0; mi < 2; mi++) af[mi] = *(const short8*)&As[(wr * 32 + mi * 16 + fr) * 32 + q8];
    #pragma unroll
    for (int ni = 0; ni < 4; ni++) bfr[ni] = *(const short8*)&Bs[(wc * 64 + ni * 16 + fr) * 32 + q8];
    #pragma unroll
    for (int mi = 0; mi < 2; mi++)
      #pragma unroll
      for (int ni = 0; ni < 4; ni++)
        acc[mi][ni] = __builtin_amdgcn_mfma_f32_16x16x32_bf16(af[mi], bfr[ni], acc[mi][ni], 0, 0, 0);
    __syncthreads();
  }

  const int colb = n0 + wc * 64 + fr;
  const int rowb = m0 + wr * 32 + (ln >> 4) * 4;
  #pragma unroll
  for (int mi = 0; mi < 2; mi++)
    #pragma unroll
    for (int r = 0; r < 4; r++) {
      const int mr = rowb + mi * 16 + r;
      #pragma unroll
      for (int ni = 0; ni < 4; ni++)
        Cg[((long)bz << 20) + (long)mr * 512 + colb + ni * 16] = f2bf(acc[mi][ni][r]);
    }
}

// ---------------- pixel-major phi/theta conv: TPT2 = imgT · W^T + b --------
__global__ __launch_bounds__(256)
void conv_pt(const short* __restrict__ imgT,
             const short* __restrict__ wth, const short* __restrict__ wph,
             const float* __restrict__ bth, const float* __restrict__ bph,
             short* __restrict__ TPT2)
{
  __shared__ __align__(16) short As[128 * 32];
  __shared__ __align__(16) short Bs[128 * 32];
  const int m0 = blockIdx.y * 128;
  const int n0 = blockIdx.x * 128;
  const bool isphi = blockIdx.y >= 256;
  const short* A = imgT + (long)m0 * 512;
  const short* B = isphi ? wph : wth;
  const float* bias = isphi ? bph : bth;
  const int t = threadIdx.x;
  const int wv = t >> 6, ln = t & 63;
  const int wm = (wv >> 1) * 64, wn = (wv & 1) * 64;
  const int fr = ln & 15, q8 = (ln >> 4) * 8;
  const int rowA = t >> 2, kc = (t & 3) * 8;

  f32x4 acc[4][4];
  #pragma unroll
  for (int i = 0; i < 4; i++)
    #pragma unroll
    for (int j = 0; j < 4; j++)
      #pragma unroll
      for (int r = 0; r < 4; r++) acc[i][j][r] = 0.f;

  for (int kk = 0; kk < 512; kk += 32) {
    #pragma unroll
    for (int s = 0; s < 2; s++) {
      async_ld16(A + (long)(s * 64 + rowA) * 512 + kk + kc, As + (s * 256 + wv * 64) * 8);
      async_ld16(B + (long)(n0 + s * 64 + rowA) * 512 + kk + kc, Bs + (s * 256 + wv * 64) * 8);
    }
    __syncthreads();
    short8 af[4], bfr[4];
    #pragma unroll
    for (int mi = 0; mi < 4; mi++) af[mi] = *(const short8*)&As[(wm + mi * 16 + fr) * 32 + q8];
    #pragma unroll
    for (int ni = 0; ni < 4; ni++) bfr[ni] = *(const short8*)&Bs[(wn + ni * 16 + fr) * 32 + q8];
    #pragma unroll
    for (int mi = 0; mi < 4; mi++)
      #pragma unroll
      for (int ni = 0; ni < 4; ni++)
        acc[mi][ni] = __builtin_amdgcn_mfma_f32_16x16x32_bf16(af[mi], bfr[ni], acc[mi][ni], 0, 0, 0);
    __syncthreads();
  }

  const int colb = n0 + wn + fr;
  const int rowb = m0 + wm + (ln >> 4) * 4;
  float cb[4];
  #pragma unroll
  for (int ni = 0; ni < 4; ni++) cb[ni] = bias[colb + ni * 16];
  #pragma unroll
  for (int mi = 0; mi < 4; mi++)
    #pragma unroll
    for (int r = 0; r < 4; r++) {
      const long mr = rowb + mi * 16 + r;
      #pragma unroll
      for (int ni = 0; ni < 4; ni++)
        TPT2[mr * 256 + colb + ni * 16] = f2bf(acc[mi][ni][r] + cb[ni]);
    }
}

// ---------------- scores: E = exp(TT2·PT2^T), fused column partial sums ----
__global__ __launch_bounds__(256)
void scores_k(const short* __restrict__ TT2, const short* __restrict__ PT2,
              short* __restrict__ ST, float* __restrict__ pstats)
{
  __shared__ __align__(16) short As[128 * 32];
  __shared__ __align__(16) short Bs[128 * 32];
  const int bz = blockIdx.z, by = blockIdx.y, bx = blockIdx.x;
  const int t = threadIdx.x;
  const int wv = t >> 6, ln = t & 63;
  const int wm = (wv >> 1) * 64, wn = (wv & 1) * 64;
  const int fr = ln & 15, q8 = (ln >> 4) * 8;
  const int rowA = t >> 2, kc = (t & 3) * 8;

  f32x4 acc[4][4];
  #pragma unroll
  for (int i = 0; i < 4; i++)
    #pragma unroll
    for (int j = 0; j < 4; j++)
      #pragma unroll
      for (int r = 0; r < 4; r++) acc[i][j][r] = 0.f;

  #pragma unroll
  for (int h = 0; h < 2; h++) {
    const short* Aseg = TT2 + ((long)(bz * 4096 + h * 2048 + by * 128)) * 256;
    const short* Bseg = PT2 + ((long)(bz * 4096 + h * 2048 + bx * 128)) * 256;
    for (int kk = 0; kk < 256; kk += 32) {
      #pragma unroll
      for (int s = 0; s < 2; s++) {
        async_ld16(Aseg + (long)(s * 64 + rowA) * 256 + kk + kc, As + (s * 256 + wv * 64) * 8);
        async_ld16(Bseg + (long)(s * 64 + rowA) * 256 + kk + kc, Bs + (s * 256 + wv * 64) * 8);
      }
      __syncthreads();
      short8 af[4], bfr[4];
      #pragma unroll
      for (int mi = 0; mi < 4; mi++) af[mi] = *(const short8*)&As[(wm + mi * 16 + fr) * 32 + q8];
      #pragma unroll
      for (int ni = 0; ni < 4; ni++) bfr[ni] = *(const short8*)&Bs[(wn + ni * 16 + fr) * 32 + q8];
      #pragma unroll
      for (int mi = 0; mi < 4; mi++)
        #pragma unroll
        for (int ni = 0; ni < 4; ni++)
          acc[mi][ni] = __builtin_amdgcn_mfma_f32_16x16x32_bf16(af[mi], bfr[ni], acc[mi][ni], 0, 0, 0);
      __syncthreads();
    }
  }

  const int colb = bx * 128 + wn + fr;
  const int rowb = by * 128 + wm + (ln >> 4) * 4;
  short* base = ST + ((long)bz << 22);
  float ps[4] = {0.f, 0.f, 0.f, 0.f};
  #pragma unroll
  for (int mi = 0; mi < 4; mi++)
    #pragma unroll
    for (int r = 0; r < 4; r++) {
      const long mr = rowb + mi * 16 + r;
      #pragma unroll
      for (int ni = 0; ni < 4; ni++) {
        float e = __expf(acc[mi][ni][r]);
        base[mr * 2048 + colb + ni * 16] = f2bf(e);
        ps[ni] += e;
      }
    }
  #pragma unroll
  for (int ni = 0; ni < 4; ni++) {
    ps[ni] += __shfl_xor(ps[ni], 16);
    ps[ni] += __shfl_xor(ps[ni], 32);
  }
  float* part = (float*)As;
  if (ln < 16) {
    #pragma unroll
    for (int ni = 0; ni < 4; ni++)
      part[(wv >> 1) * 128 + wn + ni * 16 + fr] = ps[ni];
  }
  __syncthreads();
  if (t < 128)
    pstats[((long)(bz * 16 + by)) * 2048 + bx * 128 + t] = part[t] + part[128 + t];
}

// ---------------- reduce 16 partials -> invZ per column --------------------
__global__ __launch_bounds__(256)
void zfinal(const float* __restrict__ pstats, float* __restrict__ invZ)
{
  const int g = blockIdx.x * 256 + threadIdx.x;
  const int b = g >> 11, col = g & 2047;
  float S = 0.f;
  #pragma unroll
  for (int rc = 0; rc < 16; rc++) S += pstats[((long)(b * 16 + rc)) * 2048 + col];
  invZ[g] = 1.f / S;
}

// ---------------- G *= invZ[m] (in place) ----------------------------------
__global__ __launch_bounds__(256)
void g_scale(short* __restrict__ G, const float* __restrict__ invZ)
{
  const long base = ((long)blockIdx.x * 256 + threadIdx.x) * 8;
  const int bz = (int)(base >> 20);
  const int n2 = (int)(base & 4095);
  const float* z = invZ + bz * 2048 + (n2 & 2047);
  short8 v = *(short8*)&G[base];
  f32x4 z0 = *(const f32x4*)z;
  f32x4 z1 = *(const f32x4*)(z + 4);
  #pragma unroll
  for (int j = 0; j < 4; j++) { v[j] = f2bf(bf2f(v[j]) * z0[j]); v[4 + j] = f2bf(bf2f(v[4 + j]) * z1[j]); }
  *(short8*)&G[base] = v;
}

// ---------------- mask GEMM ------------------------------------------------
__global__ __launch_bounds__(256)
void mask_k(const short* __restrict__ Wm20, const short* __restrict__ Wm21,
            const short* __restrict__ OVT, const float* __restrict__ bmask,
            const float* __restrict__ x, float* __restrict__ out)
{
  __shared__ __align__(16) short As[128 * 32];
  __shared__ __align__(16) short Bs[128 * 32];
  const int bz = blockIdx.z;
  const int n0 = blockIdx.x * 128;
  const int m0 = blockIdx.y * 128;
  const short* A = (n0 >= 2048) ? Wm21 : Wm20;
  const short* B = OVT + ((long)bz << 20) + (long)(n0 & 2047) * 512;
  const int t = threadIdx.x;
  const int wv = t >> 6, ln = t & 63;
  const int wm = (wv >> 1) * 64, wn = (wv & 1) * 64;
  const int fr = ln & 15, q8 = (ln >> 4) * 8;
  const int rowA = t >> 2, kc = (t & 3) * 8;

  f32x4 acc[4][4];
  #pragma unroll
  for (int i = 0; i < 4; i++)
    #pragma unroll
    for (int j = 0; j < 4; j++)
      #pragma unroll
      for (int r = 0; r < 4; r++) acc[i][j][r] = 0.f;

  for (int kk = 0; kk < 512; kk += 32) {
    #pragma unroll
    for (int s = 0; s < 2; s++) {
      async_ld16(A + (long)(m0 + s * 64 + rowA) * 512 + kk + kc, As + (s * 256 + wv * 64) * 8);
      async_ld16(B + (long)(s * 64 + rowA) * 512 + kk + kc, Bs + (s * 256 + wv * 64) * 8);
    }
    __syncthreads();
    short8 af[4], bfr[4];
    #pragma unroll
    for (int mi = 0; mi < 4; mi++) af[mi] = *(const short8*)&As[(wm + mi * 16 + fr) * 32 + q8];
    #pragma unroll
    for (int ni = 0; ni < 4; ni++) bfr[ni] = *(const short8*)&Bs[(wn + ni * 16 + fr) * 32 + q8];
    #pragma unroll
    for (int mi = 0; mi < 4; mi++)
      #pragma unroll
      for (int ni = 0; ni < 4; ni++)
        acc[mi][ni] = __builtin_amdgcn_mfma_f32_16x16x32_bf16(af[mi], bfr[ni], acc[mi][ni], 0, 0, 0);
    __syncthreads();
  }

  const int colb = n0 + wn + fr;
  const int rowb = m0 + wm + (ln >> 4) * 4;
  #pragma unroll
  for (int mi = 0; mi < 4; mi++)
    #pragma unroll
    for (int r = 0; r < 4; r++) {
      const int mr = rowb + mi * 16 + r;
      const float badd = bmask[mr];
      const long rbase = ((long)bz * 512 + mr) * 4096;
      #pragma unroll
      for (int ni = 0; ni < 4; ni++) {
        const int cc = colb + ni * 16;
        out[rbase + cc] = acc[mi][ni][r] + badd + x[rbase + cc];
      }
    }
}

// ---------------- weight prep ----------------------------------------------
__global__ __launch_bounds__(256)
void wconv2(const float* w_phi, const float* w_theta, const float* w_g,
            const float* w_mask,
            short* wph, short* wth, short* wg, short* Wm20, short* Wm21)
{
  const int seg = blockIdx.x >> 6;
  const int blk = blockIdx.x & 63;
  const int i0 = blk * 2048 + threadIdx.x * 8;
  if (seg < 3) {
    const float* s = seg == 0 ? w_phi : seg == 1 ? w_theta : w_g;
    short* d = seg == 0 ? wph : seg == 1 ? wth : wg;
    f32x4 a = *(const f32x4*)&s[i0];
    f32x4 b = *(const f32x4*)&s[i0 + 4];
    short8 o;
    #pragma unroll
    for (int j = 0; j < 4; j++) { o[j] = f2bf(a[j]); o[4 + j] = f2bf(b[j]); }
    *(short8*)&d[i0] = o;
  } else {
    const int o = i0 >> 8;
    f32x4 a = *(const f32x4*)&w_mask[i0];
    f32x4 b = *(const f32x4*)&w_mask[i0 + 4];
    short v[8];
    #pragma unroll
    for (int j = 0; j < 4; j++) { v[j] = f2bf(a[j]); v[4 + j] = f2bf(b[j]); }
    short8 a0, a1, b0, b1;
    #pragma unroll
    for (int j = 0; j < 4; j++) {
      a0[2 * j] = v[j];     a0[2 * j + 1] = 0;
      a1[2 * j] = v[4 + j]; a1[2 * j + 1] = 0;
      b0[2 * j] = 0;        b0[2 * j + 1] = v[j];
      b1[2 * j] = 0;        b1[2 * j + 1] = v[4 + j];
    }
    const long base = (long)o * 512 + 2 * (i0 & 255);
    *(short8*)&Wm20[base] = a0; *(short8*)&Wm20[base + 8] = a1;
    *(short8*)&Wm21[base] = b0; *(short8*)&Wm21[base + 8] = b1;
  }
}

// ---------------- convert + transpose v3 -----------------------------------
// img[b][512][4096] f32 -> imgT[b][4096][512] bf16.
// Tile: 64 px x 512 c (FULL channel dim) per block, 512 threads.
//  - phase 1: each thread loads 8 consecutive c-rows x 4 px (f32x4 each,
//    256B/row/wave coalesced), transposes 4x8 in registers, writes 8x
//    ds_write_b128. LDS row stride 520 shorts -> every b128 access spreads
//    8 lanes per bank-quad = the 8-cycle minimum (conflict-free).
//  - phase 2: each wave reads one full 512-c px row from LDS (b128) and
//    stores it as ONE contiguous 1KB global write; the whole block emits a
//    fully contiguous 64KB region.
//  - XCD slab order: L = xcd + 8k -> slab = xcd*128 + k, so consecutive k on
//    one XCD walk adjacent px windows of the same image: concurrent blocks
//    on an XCD consume adjacent 256B chunks of the SAME 16KB source rows
//    (DRAM row-buffer locality, single-XCD L2 ownership per row).
__global__ __launch_bounds__(512, 4)
void convtr(const float* __restrict__ x, const float* __restrict__ y,
            short* __restrict__ xT, short* __restrict__ yT)
{
  __shared__ __align__(16) short Ts[64 * 520];
  const int L = blockIdx.x;
  const int xcd = L & 7, k = L >> 3;
  const int slab = xcd * 128 + k;          // 0..1023, bijective
  const int z = slab >> 6;                 // 0..15 (image: 8 of x, 8 of y)
  const int pw = slab & 63;                // px window
  const float* src = (z < 8 ? x : y) + (long)(z & 7) * 512 * 4096;
  short* dst = (z < 8 ? xT : yT) + (long)(z & 7) * 4096 * 512;
  const int n0 = pw * 64;
  const int t = threadIdx.x;
  const int i16 = t & 15;                  // px quad (4 px)
  const int rb = t >> 4;                   // c octet 0..31

  // phase 1: load + in-register transpose + b128 LDS writes
  #pragma unroll
  for (int h = 0; h < 2; h++) {
    f32x4 v[8];
    #pragma unroll
    for (int j = 0; j < 8; j++)
      v[j] = *(const f32x4*)&src[(long)(h * 256 + rb * 8 + j) * 4096 + n0 + i16 * 4];
    #pragma unroll
    for (int j2 = 0; j2 < 4; j2++) {
      short8 o;
      #pragma unroll
      for (int j = 0; j < 8; j++) o[j] = f2bf(v[j][j2]);
      *(short8*)&Ts[(i16 * 4 + j2) * 520 + h * 256 + rb * 8] = o;
    }
  }
  __syncthreads();

  // phase 2: one full 1KB contiguous px-row per wave per iteration
  #pragma unroll
  for (int r = 0; r < 8; r++) {
    const int idx = r * 512 + t;
    const int px = idx >> 6;               // 0..63 (uniform per wave)
    const int c8 = idx & 63;               // c chunk of 8
    short8 o = *(const short8*)&Ts[px * 520 + c8 * 8];
    *(short8*)&dst[(long)(n0 + px) * 512 + c8 * 8] = o;
  }
}

// ---------------------------------------------------------------------------
extern "C" void kernel_launch(void* const* d_in, const int* in_sizes, int n_in,
                              void* d_out, int out_size, void* d_ws, size_t ws_size,
                              hipStream_t stream)
{
  (void)in_sizes; (void)n_in; (void)out_size; (void)ws_size;
  const float* x       = (const float*)d_in[0];
  const float* y       = (const float*)d_in[1];
  const float* w_phi   = (const float*)d_in[2];
  const float* b_phi   = (const float*)d_in[3];
  const float* w_theta = (const float*)d_in[4];
  const float* b_theta = (const float*)d_in[5];
  const float* w_g     = (const float*)d_in[6];
  const float* b_g     = (const float*)d_in[7];
  const float* w_mask  = (const float*)d_in[8];
  const float* b_mask  = (const float*)d_in[9];
  float* out = (float*)d_out;

  char* ws = (char*)d_ws;
  const long MB = 1L << 20;
  short* wph  = (short*)(ws + 0);
  short* wth  = (short*)(ws + 256 * 1024);
  short* wg   = (short*)(ws + 512 * 1024);
  short* Wm20 = (short*)(ws + 768 * 1024);
  short* Wm21 = (short*)(ws + 1280 * 1024);
  short* xT   = (short*)(ws + 2 * MB);    // [8][4096][512], 32MB
  short* yT   = (short*)(ws + 34 * MB);   // 32MB
  short* TPT2 = (short*)(ws + 66 * MB);   // [65536][256], 32MB
  short* G    = (short*)(ws + 98 * MB);   // [8][256][4096], 16MB
  short* ST   = (short*)(ws + 2 * MB);    // [8][2048][2048] E, 64MB (over xT/yT)
  float* pstats = (float*)(ws + 114 * MB);
  float* invZ   = (float*)(ws + 115 * MB);
  short* OVT  = (short*)(ws + 66 * MB);   // [8][2048][512], 16MB (over TPT2)

  dim3 blk(256, 1, 1);
  dim3 blk8(512, 1, 1);

  wconv2<<<dim3(256, 1, 1), blk, 0, stream>>>(w_phi, w_theta, w_g, w_mask,
                                              wph, wth, wg, Wm20, Wm21);
  convtr<<<dim3(1024, 1, 1), blk8, 0, stream>>>(x, y, xT, yT);

  conv_pt<<<dim3(2, 512, 1), blk, 0, stream>>>(xT, wth, wph, b_theta, b_phi, TPT2);

  gemm8<EPI_BF16_BIAS><<<dim3(32, 2, 8), blk8, 0, stream>>>(
      wg, 0, 512, xT, 4096L * 512, 512, G, 1048576L, 4096, 512, b_g);

  scores_k<<<dim3(16, 16, 8), blk, 0, stream>>>(TPT2, TPT2 + 32768L * 256, ST, pstats);
  zfinal<<<dim3(64, 1, 1), blk, 0, stream>>>(pstats, invZ);
  g_scale<<<dim3(4096, 1, 1), blk, 0, stream>>>(G, invZ);

  ov_k<<<dim3(512, 1, 1), blk8, 0, stream>>>(ST, G, OVT);

  mask_k<<<dim3(32, 4, 8), blk, 0, stream>>>(Wm20, Wm21, OVT, b_mask, x, out);
}

// Round 3
// 394.321 us; speedup vs baseline: 1.0445x; 1.0445x over previous
//
#include <hip/hip_runtime.h>
#include <hip/hip_bf16.h>

// Non-local block, B=8 C=512 H=W=64, IC=256, N2=HW=4096, N=2048 (folded).
//
// Round-7 (resubmit; round-2 bench was an infra failure, kernel audited):
// convtr v4 — 256px x 128c tile so every wave READ is one full 1KB
// contiguous row chunk (the read-granularity experiment; v2/v3 both had 256B
// read segments and identical perf). Writes are 256B chunks (v2-proven ok),
// 4 c-group blocks of one px-window co-scheduled on one XCD so writes merge
// into full 1KB lines in a single L2. Swizzled LDS gives uniform 8 words/bank
// (throughput floor) on both phases. Rest identical to round 6.

typedef __attribute__((ext_vector_type(8))) short short8;
typedef __attribute__((ext_vector_type(4))) short short4v;
typedef __attribute__((ext_vector_type(4))) float f32x4;

enum { EPI_BF16 = 0, EPI_BF16_BIAS = 1 };

__device__ __forceinline__ short f2bf(float f) {
  union { __hip_bfloat16 h; short s; } u; u.h = __float2bfloat16(f); return u.s;
}
__device__ __forceinline__ float bf2f(short s) {
  union { short s; __hip_bfloat16 h; } u; u.s = s; return __bfloat162float(u.h);
}

__device__ __forceinline__ void async_ld16(const void* g, void* l) {
  __builtin_amdgcn_global_load_lds(
      (const __attribute__((address_space(1))) unsigned int*)(unsigned long long)g,
      (__attribute__((address_space(3))) unsigned int*)(unsigned int)(unsigned long long)l,
      16, 0, 0);
}

// ---------------- 8-wave 128x128 GEMM: C[i][j] = sum_k A[i][k]*BT[j][k] ----
template<int EPI>
__global__ __launch_bounds__(512, 4)
void gemm8(const short* __restrict__ Ag, long sA, int lda,
           const short* __restrict__ Bg, long sB, int ldb,
           short* __restrict__ Cg, long sC, int ldc,
           int K, const float* __restrict__ bias)
{
  __shared__ __align__(16) short As[128 * 32];
  __shared__ __align__(16) short Bs[128 * 32];
  const int bz = blockIdx.z;
  const short* A = Ag + (long)bz * sA;
  const short* B = Bg + (long)bz * sB;
  const int m0 = blockIdx.y * 128;
  const int n0 = blockIdx.x * 128;
  const int t = threadIdx.x;
  const int wv = t >> 6, ln = t & 63;
  const int wr = wv >> 1, wc = wv & 1;
  const int fr = ln & 15, q8 = (ln >> 4) * 8;
  const int rowA = t >> 2, kc = (t & 3) * 8;

  f32x4 acc[2][4];
  #pragma unroll
  for (int i = 0; i < 2; i++)
    #pragma unroll
    for (int j = 0; j < 4; j++)
      #pragma unroll
      for (int r = 0; r < 4; r++) acc[i][j][r] = 0.f;

  for (int kk = 0; kk < K; kk += 32) {
    async_ld16(A + (long)(m0 + rowA) * lda + kk + kc, As + wv * 512);
    async_ld16(B + (long)(n0 + rowA) * ldb + kk + kc, Bs + wv * 512);
    __syncthreads();
    short8 af[2], bfr[4];
    #pragma unroll
    for (int mi = 0; mi < 2; mi++) af[mi] = *(const short8*)&As[(wr * 32 + mi * 16 + fr) * 32 + q8];
    #pragma unroll
    for (int ni = 0; ni < 4; ni++) bfr[ni] = *(const short8*)&Bs[(wc * 64 + ni * 16 + fr) * 32 + q8];
    #pragma unroll
    for (int mi = 0; mi < 2; mi++)
      #pragma unroll
      for (int ni = 0; ni < 4; ni++)
        acc[mi][ni] = __builtin_amdgcn_mfma_f32_16x16x32_bf16(af[mi], bfr[ni], acc[mi][ni], 0, 0, 0);
    __syncthreads();
  }

  const int colb = n0 + wc * 64 + fr;
  const int rowb = m0 + wr * 32 + (ln >> 4) * 4;
  #pragma unroll
  for (int mi = 0; mi < 2; mi++)
    #pragma unroll
    for (int r = 0; r < 4; r++) {
      const int mr = rowb + mi * 16 + r;
      float badd = 0.f;
      if constexpr (EPI == EPI_BF16_BIAS) badd = bias[mr];
      #pragma unroll
      for (int ni = 0; ni < 4; ni++)
        Cg[(long)bz * sC + (long)mr * ldc + colb + ni * 16] = f2bf(acc[mi][ni][r] + badd);
    }
}

// ---------------- OV GEMM with XCD-locality swizzle ------------------------
// OVT[b][n][c] = sum_m E[n][m]*G''[c][m]. 512 blocks; all 4 c-blocks of one
// (b,n) E-slab land on the same XCD (launch id === slab mod 8) so the 512KB
// slab is served from that XCD's L2 after the first pull.
__global__ __launch_bounds__(512, 4)
void ov_k(const short* __restrict__ Eg, const short* __restrict__ Gg,
          short* __restrict__ Cg)
{
  const int L = blockIdx.x;
  const int xcd = L & 7, k = L >> 3;
  const int slab = xcd + ((k >> 2) << 3);   // 0..127
  const int bz = slab >> 4, by = slab & 15, bx = k & 3;

  __shared__ __align__(16) short As[128 * 32];
  __shared__ __align__(16) short Bs[128 * 32];
  const short* A = Eg + ((long)bz << 22);
  const short* B = Gg + ((long)bz << 20);
  const int m0 = by * 128;
  const int n0 = bx * 128;
  const int t = threadIdx.x;
  const int wv = t >> 6, ln = t & 63;
  const int wr = wv >> 1, wc = wv & 1;
  const int fr = ln & 15, q8 = (ln >> 4) * 8;
  const int rowA = t >> 2, kc = (t & 3) * 8;

  f32x4 acc[2][4];
  #pragma unroll
  for (int i = 0; i < 2; i++)
    #pragma unroll
    for (int j = 0; j < 4; j++)
      #pragma unroll
      for (int r = 0; r < 4; r++) acc[i][j][r] = 0.f;

  for (int kk = 0; kk < 2048; kk += 32) {
    async_ld16(A + (long)(m0 + rowA) * 2048 + kk + kc, As + wv * 512);
    async_ld16(B + (long)(n0 + rowA) * 2048 + kk + kc, Bs + wv * 512);
    __syncthreads();
    short8 af[2], bfr[4];
    #pragma unroll
    for (int mi = 0; mi < 2; mi++) af[mi] = *(const short8*)&As[(wr * 32 + mi * 16 + fr) * 32 + q8];
    #pragma unroll
    for (int ni = 0; ni < 4; ni++) bfr[ni] = *(const short8*)&Bs[(wc * 64 + ni * 16 + fr) * 32 + q8];
    #pragma unroll
    for (int mi = 0; mi < 2; mi++)
      #pragma unroll
      for (int ni = 0; ni < 4; ni++)
        acc[mi][ni] = __builtin_amdgcn_mfma_f32_16x16x32_bf16(af[mi], bfr[ni], acc[mi][ni], 0, 0, 0);
    __syncthreads();
  }

  const int colb = n0 + wc * 64 + fr;
  const int rowb = m0 + wr * 32 + (ln >> 4) * 4;
  #pragma unroll
  for (int mi = 0; mi < 2; mi++)
    #pragma unroll
    for (int r = 0; r < 4; r++) {
      const int mr = rowb + mi * 16 + r;
      #pragma unroll
      for (int ni = 0; ni < 4; ni++)
        Cg[((long)bz << 20) + (long)mr * 512 + colb + ni * 16] = f2bf(acc[mi][ni][r]);
    }
}

// ---------------- pixel-major phi/theta conv: TPT2 = imgT · W^T + b --------
__global__ __launch_bounds__(256)
void conv_pt(const short* __restrict__ imgT,
             const short* __restrict__ wth, const short* __restrict__ wph,
             const float* __restrict__ bth, const float* __restrict__ bph,
             short* __restrict__ TPT2)
{
  __shared__ __align__(16) short As[128 * 32];
  __shared__ __align__(16) short Bs[128 * 32];
  const int m0 = blockIdx.y * 128;
  const int n0 = blockIdx.x * 128;
  const bool isphi = blockIdx.y >= 256;
  const short* A = imgT + (long)m0 * 512;
  const short* B = isphi ? wph : wth;
  const float* bias = isphi ? bph : bth;
  const int t = threadIdx.x;
  const int wv = t >> 6, ln = t & 63;
  const int wm = (wv >> 1) * 64, wn = (wv & 1) * 64;
  const int fr = ln & 15, q8 = (ln >> 4) * 8;
  const int rowA = t >> 2, kc = (t & 3) * 8;

  f32x4 acc[4][4];
  #pragma unroll
  for (int i = 0; i < 4; i++)
    #pragma unroll
    for (int j = 0; j < 4; j++)
      #pragma unroll
      for (int r = 0; r < 4; r++) acc[i][j][r] = 0.f;

  for (int kk = 0; kk < 512; kk += 32) {
    #pragma unroll
    for (int s = 0; s < 2; s++) {
      async_ld16(A + (long)(s * 64 + rowA) * 512 + kk + kc, As + (s * 256 + wv * 64) * 8);
      async_ld16(B + (long)(n0 + s * 64 + rowA) * 512 + kk + kc, Bs + (s * 256 + wv * 64) * 8);
    }
    __syncthreads();
    short8 af[4], bfr[4];
    #pragma unroll
    for (int mi = 0; mi < 4; mi++) af[mi] = *(const short8*)&As[(wm + mi * 16 + fr) * 32 + q8];
    #pragma unroll
    for (int ni = 0; ni < 4; ni++) bfr[ni] = *(const short8*)&Bs[(wn + ni * 16 + fr) * 32 + q8];
    #pragma unroll
    for (int mi = 0; mi < 4; mi++)
      #pragma unroll
      for (int ni = 0; ni < 4; ni++)
        acc[mi][ni] = __builtin_amdgcn_mfma_f32_16x16x32_bf16(af[mi], bfr[ni], acc[mi][ni], 0, 0, 0);
    __syncthreads();
  }

  const int colb = n0 + wn + fr;
  const int rowb = m0 + wm + (ln >> 4) * 4;
  float cb[4];
  #pragma unroll
  for (int ni = 0; ni < 4; ni++) cb[ni] = bias[colb + ni * 16];
  #pragma unroll
  for (int mi = 0; mi < 4; mi++)
    #pragma unroll
    for (int r = 0; r < 4; r++) {
      const long mr = rowb + mi * 16 + r;
      #pragma unroll
      for (int ni = 0; ni < 4; ni++)
        TPT2[mr * 256 + colb + ni * 16] = f2bf(acc[mi][ni][r] + cb[ni]);
    }
}

// ---------------- scores: E = exp(TT2·PT2^T), fused column partial sums ----
__global__ __launch_bounds__(256)
void scores_k(const short* __restrict__ TT2, const short* __restrict__ PT2,
              short* __restrict__ ST, float* __restrict__ pstats)
{
  __shared__ __align__(16) short As[128 * 32];
  __shared__ __align__(16) short Bs[128 * 32];
  const int bz = blockIdx.z, by = blockIdx.y, bx = blockIdx.x;
  const int t = threadIdx.x;
  const int wv = t >> 6, ln = t & 63;
  const int wm = (wv >> 1) * 64, wn = (wv & 1) * 64;
  const int fr = ln & 15, q8 = (ln >> 4) * 8;
  const int rowA = t >> 2, kc = (t & 3) * 8;

  f32x4 acc[4][4];
  #pragma unroll
  for (int i = 0; i < 4; i++)
    #pragma unroll
    for (int j = 0; j < 4; j++)
      #pragma unroll
      for (int r = 0; r < 4; r++) acc[i][j][r] = 0.f;

  #pragma unroll
  for (int h = 0; h < 2; h++) {
    const short* Aseg = TT2 + ((long)(bz * 4096 + h * 2048 + by * 128)) * 256;
    const short* Bseg = PT2 + ((long)(bz * 4096 + h * 2048 + bx * 128)) * 256;
    for (int kk = 0; kk < 256; kk += 32) {
      #pragma unroll
      for (int s = 0; s < 2; s++) {
        async_ld16(Aseg + (long)(s * 64 + rowA) * 256 + kk + kc, As + (s * 256 + wv * 64) * 8);
        async_ld16(Bseg + (long)(s * 64 + rowA) * 256 + kk + kc, Bs + (s * 256 + wv * 64) * 8);
      }
      __syncthreads();
      short8 af[4], bfr[4];
      #pragma unroll
      for (int mi = 0; mi < 4; mi++) af[mi] = *(const short8*)&As[(wm + mi * 16 + fr) * 32 + q8];
      #pragma unroll
      for (int ni = 0; ni < 4; ni++) bfr[ni] = *(const short8*)&Bs[(wn + ni * 16 + fr) * 32 + q8];
      #pragma unroll
      for (int mi = 0; mi < 4; mi++)
        #pragma unroll
        for (int ni = 0; ni < 4; ni++)
          acc[mi][ni] = __builtin_amdgcn_mfma_f32_16x16x32_bf16(af[mi], bfr[ni], acc[mi][ni], 0, 0, 0);
      __syncthreads();
    }
  }

  const int colb = bx * 128 + wn + fr;
  const int rowb = by * 128 + wm + (ln >> 4) * 4;
  short* base = ST + ((long)bz << 22);
  float ps[4] = {0.f, 0.f, 0.f, 0.f};
  #pragma unroll
  for (int mi = 0; mi < 4; mi++)
    #pragma unroll
    for (int r = 0; r < 4; r++) {
      const long mr = rowb + mi * 16 + r;
      #pragma unroll
      for (int ni = 0; ni < 4; ni++) {
        float e = __expf(acc[mi][ni][r]);
        base[mr * 2048 + colb + ni * 16] = f2bf(e);
        ps[ni] += e;
      }
    }
  #pragma unroll
  for (int ni = 0; ni < 4; ni++) {
    ps[ni] += __shfl_xor(ps[ni], 16);
    ps[ni] += __shfl_xor(ps[ni], 32);
  }
  float* part = (float*)As;
  if (ln < 16) {
    #pragma unroll
    for (int ni = 0; ni < 4; ni++)
      part[(wv >> 1) * 128 + wn + ni * 16 + fr] = ps[ni];
  }
  __syncthreads();
  if (t < 128)
    pstats[((long)(bz * 16 + by)) * 2048 + bx * 128 + t] = part[t] + part[128 + t];
}

// ---------------- reduce 16 partials -> invZ per column --------------------
__global__ __launch_bounds__(256)
void zfinal(const float* __restrict__ pstats, float* __restrict__ invZ)
{
  const int g = blockIdx.x * 256 + threadIdx.x;
  const int b = g >> 11, col = g & 2047;
  float S = 0.f;
  #pragma unroll
  for (int rc = 0; rc < 16; rc++) S += pstats[((long)(b * 16 + rc)) * 2048 + col];
  invZ[g] = 1.f / S;
}

// ---------------- G *= invZ[m] (in place) ----------------------------------
__global__ __launch_bounds__(256)
void g_scale(short* __restrict__ G, const float* __restrict__ invZ)
{
  const long base = ((long)blockIdx.x * 256 + threadIdx.x) * 8;
  const int bz = (int)(base >> 20);
  const int n2 = (int)(base & 4095);
  const float* z = invZ + bz * 2048 + (n2 & 2047);
  short8 v = *(short8*)&G[base];
  f32x4 z0 = *(const f32x4*)z;
  f32x4 z1 = *(const f32x4*)(z + 4);
  #pragma unroll
  for (int j = 0; j < 4; j++) { v[j] = f2bf(bf2f(v[j]) * z0[j]); v[4 + j] = f2bf(bf2f(v[4 + j]) * z1[j]); }
  *(short8*)&G[base] = v;
}

// ---------------- mask GEMM ------------------------------------------------
__global__ __launch_bounds__(256)
void mask_k(const short* __restrict__ Wm20, const short* __restrict__ Wm21,
            const short* __restrict__ OVT, const float* __restrict__ bmask,
            const float* __restrict__ x, float* __restrict__ out)
{
  __shared__ __align__(16) short As[128 * 32];
  __shared__ __align__(16) short Bs[128 * 32];
  const int bz = blockIdx.z;
  const int n0 = blockIdx.x * 128;
  const int m0 = blockIdx.y * 128;
  const short* A = (n0 >= 2048) ? Wm21 : Wm20;
  const short* B = OVT + ((long)bz << 20) + (long)(n0 & 2047) * 512;
  const int t = threadIdx.x;
  const int wv = t >> 6, ln = t & 63;
  const int wm = (wv >> 1) * 64, wn = (wv & 1) * 64;
  const int fr = ln & 15, q8 = (ln >> 4) * 8;
  const int rowA = t >> 2, kc = (t & 3) * 8;

  f32x4 acc[4][4];
  #pragma unroll
  for (int i = 0; i < 4; i++)
    #pragma unroll
    for (int j = 0; j < 4; j++)
      #pragma unroll
      for (int r = 0; r < 4; r++) acc[i][j][r] = 0.f;

  for (int kk = 0; kk < 512; kk += 32) {
    #pragma unroll
    for (int s = 0; s < 2; s++) {
      async_ld16(A + (long)(m0 + s * 64 + rowA) * 512 + kk + kc, As + (s * 256 + wv * 64) * 8);
      async_ld16(B + (long)(s * 64 + rowA) * 512 + kk + kc, Bs + (s * 256 + wv * 64) * 8);
    }
    __syncthreads();
    short8 af[4], bfr[4];
    #pragma unroll
    for (int mi = 0; mi < 4; mi++) af[mi] = *(const short8*)&As[(wm + mi * 16 + fr) * 32 + q8];
    #pragma unroll
    for (int ni = 0; ni < 4; ni++) bfr[ni] = *(const short8*)&Bs[(wn + ni * 16 + fr) * 32 + q8];
    #pragma unroll
    for (int mi = 0; mi < 4; mi++)
      #pragma unroll
      for (int ni = 0; ni < 4; ni++)
        acc[mi][ni] = __builtin_amdgcn_mfma_f32_16x16x32_bf16(af[mi], bfr[ni], acc[mi][ni], 0, 0, 0);
    __syncthreads();
  }

  const int colb = n0 + wn + fr;
  const int rowb = m0 + wm + (ln >> 4) * 4;
  #pragma unroll
  for (int mi = 0; mi < 4; mi++)
    #pragma unroll
    for (int r = 0; r < 4; r++) {
      const int mr = rowb + mi * 16 + r;
      const float badd = bmask[mr];
      const long rbase = ((long)bz * 512 + mr) * 4096;
      #pragma unroll
      for (int ni = 0; ni < 4; ni++) {
        const int cc = colb + ni * 16;
        out[rbase + cc] = acc[mi][ni][r] + badd + x[rbase + cc];
      }
    }
}

// ---------------- weight prep ----------------------------------------------
__global__ __launch_bounds__(256)
void wconv2(const float* w_phi, const float* w_theta, const float* w_g,
            const float* w_mask,
            short* wph, short* wth, short* wg, short* Wm20, short* Wm21)
{
  const int seg = blockIdx.x >> 6;
  const int blk = blockIdx.x & 63;
  const int i0 = blk * 2048 + threadIdx.x * 8;
  if (seg < 3) {
    const float* s = seg == 0 ? w_phi : seg == 1 ? w_theta : w_g;
    short* d = seg == 0 ? wph : seg == 1 ? wth : wg;
    f32x4 a = *(const f32x4*)&s[i0];
    f32x4 b = *(const f32x4*)&s[i0 + 4];
    short8 o;
    #pragma unroll
    for (int j = 0; j < 4; j++) { o[j] = f2bf(a[j]); o[4 + j] = f2bf(b[j]); }
    *(short8*)&d[i0] = o;
  } else {
    const int o = i0 >> 8;
    f32x4 a = *(const f32x4*)&w_mask[i0];
    f32x4 b = *(const f32x4*)&w_mask[i0 + 4];
    short v[8];
    #pragma unroll
    for (int j = 0; j < 4; j++) { v[j] = f2bf(a[j]); v[4 + j] = f2bf(b[j]); }
    short8 a0, a1, b0, b1;
    #pragma unroll
    for (int j = 0; j < 4; j++) {
      a0[2 * j] = v[j];     a0[2 * j + 1] = 0;
      a1[2 * j] = v[4 + j]; a1[2 * j + 1] = 0;
      b0[2 * j] = 0;        b0[2 * j + 1] = v[j];
      b1[2 * j] = 0;        b1[2 * j + 1] = v[4 + j];
    }
    const long base = (long)o * 512 + 2 * (i0 & 255);
    *(short8*)&Wm20[base] = a0; *(short8*)&Wm20[base + 8] = a1;
    *(short8*)&Wm21[base] = b0; *(short8*)&Wm21[base + 8] = b1;
  }
}

// ---------------- convert + transpose v4 -----------------------------------
// img[b][512][4096] f32 -> imgT[b][4096][512] bf16.
// Tile: 256 px x 128 c per block, 512 threads, 64KB LDS.
//  - phase 1: wave wv reads c-rows wv*16+j (j=0..15); lane l holds px
//    l*4..l*4+3 -> every load instr is ONE FULL 1KB contiguous row chunk.
//    In-register 4x16 transpose; b128 LDS writes with granule swizzle
//    g' = g ^ ((px>>2)&15) -> uniform 8 words/bank (throughput floor).
//  - phase 2: b128 LDS reads (same swizzle, uniform banks), stores 256B
//    per px row at 1KB stride (v2-proven pattern).
//  - XCD slab map: the 4 c-group blocks of one (img,pw) dispatch adjacently
//    on ONE XCD, so their 4x256B chunks of each output row merge into full
//    1KB lines in that XCD's L2 before write-back.
__global__ __launch_bounds__(512, 4)
void convtr(const float* __restrict__ x, const float* __restrict__ y,
            short* __restrict__ xT, short* __restrict__ yT)
{
  __shared__ __align__(16) short Ts[256 * 128];
  const int L = blockIdx.x;
  const int xcd = L & 7, k = L >> 3;
  const int slab = xcd * 32 + (k >> 2);    // 0..255, bijective
  const int img = slab >> 4;               // 0..15 (8 of x, 8 of y)
  const int pw  = slab & 15;               // px window (256 px)
  const int cg  = k & 3;                   // c-group (128 c)
  const float* src = (img < 8 ? x : y) + (long)(img & 7) * 512 * 4096;
  short* dst = (img < 8 ? xT : yT) + (long)(img & 7) * 4096 * 512;
  const int n0 = pw * 256;
  const int c0 = cg * 128;
  const int t = threadIdx.x;
  const int wv = t >> 6, l = t & 63;

  // phase 1: 16 full-1KB wave reads, in-register transpose, swizzled writes
  f32x4 v[16];
  #pragma unroll
  for (int j = 0; j < 16; j++)
    v[j] = *(const f32x4*)&src[(long)(c0 + wv * 16 + j) * 4096 + n0 + l * 4];
  #pragma unroll
  for (int j2 = 0; j2 < 4; j2++) {
    const int px = l * 4 + j2;
    const int sw = (px >> 2) & 15;         // == l & 15
    #pragma unroll
    for (int h = 0; h < 2; h++) {
      short8 o;
      #pragma unroll
      for (int cc = 0; cc < 8; cc++) o[cc] = f2bf(v[h * 8 + cc][j2]);
      const int g = wv * 2 + h;            // granule (8 c) within 128-c row
      *(short8*)&Ts[px * 128 + ((g ^ sw) * 8)] = o;
    }
  }
  __syncthreads();

  // phase 2: b128 reads + 256B-contiguous global stores (4 px per instr)
  #pragma unroll
  for (int it = 0; it < 8; it++) {
    const int idx = it * 512 + t;
    const int px = idx >> 4, g = idx & 15;
    const int g2 = g ^ ((px >> 2) & 15);
    short8 o = *(const short8*)&Ts[px * 128 + g2 * 8];
    *(short8*)&dst[(long)(n0 + px) * 512 + c0 + g * 8] = o;
  }
}

// ---------------------------------------------------------------------------
extern "C" void kernel_launch(void* const* d_in, const int* in_sizes, int n_in,
                              void* d_out, int out_size, void* d_ws, size_t ws_size,
                              hipStream_t stream)
{
  (void)in_sizes; (void)n_in; (void)out_size; (void)ws_size;
  const float* x       = (const float*)d_in[0];
  const float* y       = (const float*)d_in[1];
  const float* w_phi   = (const float*)d_in[2];
  const float* b_phi   = (const float*)d_in[3];
  const float* w_theta = (const float*)d_in[4];
  const float* b_theta = (const float*)d_in[5];
  const float* w_g     = (const float*)d_in[6];
  const float* b_g     = (const float*)d_in[7];
  const float* w_mask  = (const float*)d_in[8];
  const float* b_mask  = (const float*)d_in[9];
  float* out = (float*)d_out;

  char* ws = (char*)d_ws;
  const long MB = 1L << 20;
  short* wph  = (short*)(ws + 0);
  short* wth  = (short*)(ws + 256 * 1024);
  short* wg   = (short*)(ws + 512 * 1024);
  short* Wm20 = (short*)(ws + 768 * 1024);
  short* Wm21 = (short*)(ws + 1280 * 1024);
  short* xT   = (short*)(ws + 2 * MB);    // [8][4096][512], 32MB
  short* yT   = (short*)(ws + 34 * MB);   // 32MB
  short* TPT2 = (short*)(ws + 66 * MB);   // [65536][256], 32MB
  short* G    = (short*)(ws + 98 * MB);   // [8][256][4096], 16MB
  short* ST   = (short*)(ws + 2 * MB);    // [8][2048][2048] E, 64MB (over xT/yT)
  float* pstats = (float*)(ws + 114 * MB);
  float* invZ   = (float*)(ws + 115 * MB);
  short* OVT  = (short*)(ws + 66 * MB);   // [8][2048][512], 16MB (over TPT2)

  dim3 blk(256, 1, 1);
  dim3 blk8(512, 1, 1);

  wconv2<<<dim3(256, 1, 1), blk, 0, stream>>>(w_phi, w_theta, w_g, w_mask,
                                              wph, wth, wg, Wm20, Wm21);
  convtr<<<dim3(1024, 1, 1), blk8, 0, stream>>>(x, y, xT, yT);

  conv_pt<<<dim3(2, 512, 1), blk, 0, stream>>>(xT, wth, wph, b_theta, b_phi, TPT2);

  gemm8<EPI_BF16_BIAS><<<dim3(32, 2, 8), blk8, 0, stream>>>(
      wg, 0, 512, xT, 4096L * 512, 512, G, 1048576L, 4096, 512, b_g);

  scores_k<<<dim3(16, 16, 8), blk, 0, stream>>>(TPT2, TPT2 + 32768L * 256, ST, pstats);
  zfinal<<<dim3(64, 1, 1), blk, 0, stream>>>(pstats, invZ);
  g_scale<<<dim3(4096, 1, 1), blk, 0, stream>>>(G, invZ);

  ov_k<<<dim3(512, 1, 1), blk8, 0, stream>>>(ST, G, OVT);

  mask_k<<<dim3(32, 4, 8), blk, 0, stream>>>(Wm20, Wm21, OVT, b_mask, x, out);
}

// Round 4
// 375.527 us; speedup vs baseline: 1.0967x; 1.0500x over previous
//
#include <hip/hip_runtime.h>
#include <hip/hip_bf16.h>

// Non-local block, B=8 C=512 H=W=64, IC=256, N2=HW=4096, N=2048 (folded).
//
// Round-8: convtr ELIMINATED. The f32->bf16 transpose is fused into the two
// consumers' LDS staging (conv_ptf, gemmG_f): per K-step, load f32 [32c][128px]
// (512B-coalesced rows), in-register 4x4 transpose + cvt, ds_write_b64 into a
// 16B-unit XOR-swizzled [128px][32c] bf16 tile (conflict-free b128 frag reads).
// Weights keep the async global_load_lds path. Saves 128MB of HBM traffic and
// one dispatch. Rest identical to round 7.

typedef __attribute__((ext_vector_type(8))) short short8;
typedef __attribute__((ext_vector_type(4))) short short4v;
typedef __attribute__((ext_vector_type(4))) float f32x4;

enum { EPI_BF16 = 0, EPI_BF16_BIAS = 1 };

__device__ __forceinline__ short f2bf(float f) {
  union { __hip_bfloat16 h; short s; } u; u.h = __float2bfloat16(f); return u.s;
}
__device__ __forceinline__ float bf2f(short s) {
  union { short s; __hip_bfloat16 h; } u; u.s = s; return __bfloat162float(u.h);
}

__device__ __forceinline__ void async_ld16(const void* g, void* l) {
  __builtin_amdgcn_global_load_lds(
      (const __attribute__((address_space(1))) unsigned int*)(unsigned long long)g,
      (__attribute__((address_space(3))) unsigned int*)(unsigned int)(unsigned long long)l,
      16, 0, 0);
}

// Staged transpose helper (256 staging threads): thread s handles c-quad
// g4=(s>>5)*4 (0..28) x px-quad p4=(s&31)*4. Loads 4 rows of f32x4 (each row
// 512B wave-coalesced), transposes 4x4 in registers, writes 4x ds_write_b64
// into Ds[px][c] bf16 with 16B-unit swizzle u ^= (px>>2)&3 (read-side must
// apply the same XOR). Ds row = 32 shorts (64B).
__device__ __forceinline__ void stage_tr(const float* __restrict__ src,
                                         int kk, int px0, int s, short* Ds)
{
  const int g4 = (s >> 5) * 4;
  const int p4 = (s & 31) * 4;
  f32x4 v0 = *(const f32x4*)&src[(long)(kk + g4 + 0) * 4096 + px0 + p4];
  f32x4 v1 = *(const f32x4*)&src[(long)(kk + g4 + 1) * 4096 + px0 + p4];
  f32x4 v2 = *(const f32x4*)&src[(long)(kk + g4 + 2) * 4096 + px0 + p4];
  f32x4 v3 = *(const f32x4*)&src[(long)(kk + g4 + 3) * 4096 + px0 + p4];
  #pragma unroll
  for (int j = 0; j < 4; j++) {
    short4v w;
    w[0] = f2bf(v0[j]); w[1] = f2bf(v1[j]); w[2] = f2bf(v2[j]); w[3] = f2bf(v3[j]);
    const int px = p4 + j;
    const int u = (g4 >> 3) ^ ((px >> 2) & 3);
    *(short4v*)&Ds[px * 32 + u * 8 + (g4 & 4)] = w;
  }
}

// swizzled b128 fragment read from a stage_tr tile
__device__ __forceinline__ short8 frag_sw(const short* Ds, int row, int q8)
{
  return *(const short8*)&Ds[row * 32 + (((q8 >> 3) ^ ((row >> 2) & 3)) << 3)];
}

// ---------------- OV GEMM with XCD-locality swizzle ------------------------
// OVT[b][n][c] = sum_m E[n][m]*G''[c][m]. 512 blocks; all 4 c-blocks of one
// (b,n) E-slab land on the same XCD (launch id === slab mod 8) so the 512KB
// slab is served from that XCD's L2 after the first pull.
__global__ __launch_bounds__(512, 4)
void ov_k(const short* __restrict__ Eg, const short* __restrict__ Gg,
          short* __restrict__ Cg)
{
  const int L = blockIdx.x;
  const int xcd = L & 7, k = L >> 3;
  const int slab = xcd + ((k >> 2) << 3);   // 0..127
  const int bz = slab >> 4, by = slab & 15, bx = k & 3;

  __shared__ __align__(16) short As[128 * 32];
  __shared__ __align__(16) short Bs[128 * 32];
  const short* A = Eg + ((long)bz << 22);
  const short* B = Gg + ((long)bz << 20);
  const int m0 = by * 128;
  const int n0 = bx * 128;
  const int t = threadIdx.x;
  const int wv = t >> 6, ln = t & 63;
  const int wr = wv >> 1, wc = wv & 1;
  const int fr = ln & 15, q8 = (ln >> 4) * 8;
  const int rowA = t >> 2, kc = (t & 3) * 8;

  f32x4 acc[2][4];
  #pragma unroll
  for (int i = 0; i < 2; i++)
    #pragma unroll
    for (int j = 0; j < 4; j++)
      #pragma unroll
      for (int r = 0; r < 4; r++) acc[i][j][r] = 0.f;

  for (int kk = 0; kk < 2048; kk += 32) {
    async_ld16(A + (long)(m0 + rowA) * 2048 + kk + kc, As + wv * 512);
    async_ld16(B + (long)(n0 + rowA) * 2048 + kk + kc, Bs + wv * 512);
    __syncthreads();
    short8 af[2], bfr[4];
    #pragma unroll
    for (int mi = 0; mi < 2; mi++) af[mi] = *(const short8*)&As[(wr * 32 + mi * 16 + fr) * 32 + q8];
    #pragma unroll
    for (int ni = 0; ni < 4; ni++) bfr[ni] = *(const short8*)&Bs[(wc * 64 + ni * 16 + fr) * 32 + q8];
    #pragma unroll
    for (int mi = 0; mi < 2; mi++)
      #pragma unroll
      for (int ni = 0; ni < 4; ni++)
        acc[mi][ni] = __builtin_amdgcn_mfma_f32_16x16x32_bf16(af[mi], bfr[ni], acc[mi][ni], 0, 0, 0);
    __syncthreads();
  }

  const int colb = n0 + wc * 64 + fr;
  const int rowb = m0 + wr * 32 + (ln >> 4) * 4;
  #pragma unroll
  for (int mi = 0; mi < 2; mi++)
    #pragma unroll
    for (int r = 0; r < 4; r++) {
      const int mr = rowb + mi * 16 + r;
      #pragma unroll
      for (int ni = 0; ni < 4; ni++)
        Cg[((long)bz << 20) + (long)mr * 512 + colb + ni * 16] = f2bf(acc[mi][ni][r]);
    }
}

// ---------------- fused theta/phi conv: TPT2 = T(img_f32) · W^T + b --------
// A-operand built per K-step from the ORIGINAL f32 c-major image via
// stage_tr (no xT/yT intermediate). Weights via async_ld16.
__global__ __launch_bounds__(256)
void conv_ptf(const float* __restrict__ x, const float* __restrict__ y,
              const short* __restrict__ wth, const short* __restrict__ wph,
              const float* __restrict__ bth, const float* __restrict__ bph,
              short* __restrict__ TPT2)
{
  __shared__ __align__(16) short As[128 * 32];   // [px][c] bf16, swizzled
  __shared__ __align__(16) short Bs[128 * 32];   // weights, linear
  const int m0 = blockIdx.y * 128;               // global px row (0..65535)
  const int n0 = blockIdx.x * 128;
  const bool isphi = blockIdx.y >= 256;
  const float* src = (isphi ? y : x) + ((long)((m0 >> 12) & 7)) * (512L * 4096);
  const int px0 = m0 & 4095;
  const short* B = isphi ? wph : wth;
  const float* bias = isphi ? bph : bth;
  const int t = threadIdx.x;
  const int wv = t >> 6, ln = t & 63;
  const int wm = (wv >> 1) * 64, wn = (wv & 1) * 64;
  const int fr = ln & 15, q8 = (ln >> 4) * 8;
  const int rowA = t >> 2, kc = (t & 3) * 8;

  f32x4 acc[4][4];
  #pragma unroll
  for (int i = 0; i < 4; i++)
    #pragma unroll
    for (int j = 0; j < 4; j++)
      #pragma unroll
      for (int r = 0; r < 4; r++) acc[i][j][r] = 0.f;

  for (int kk = 0; kk < 512; kk += 32) {
    #pragma unroll
    for (int s = 0; s < 2; s++)
      async_ld16(B + (long)(n0 + s * 64 + rowA) * 512 + kk + kc, Bs + (s * 256 + wv * 64) * 8);
    stage_tr(src, kk, px0, t, As);
    __syncthreads();
    short8 af[4], bfr[4];
    #pragma unroll
    for (int mi = 0; mi < 4; mi++) af[mi] = frag_sw(As, wm + mi * 16 + fr, q8);
    #pragma unroll
    for (int ni = 0; ni < 4; ni++) bfr[ni] = *(const short8*)&Bs[(wn + ni * 16 + fr) * 32 + q8];
    #pragma unroll
    for (int mi = 0; mi < 4; mi++)
      #pragma unroll
      for (int ni = 0; ni < 4; ni++)
        acc[mi][ni] = __builtin_amdgcn_mfma_f32_16x16x32_bf16(af[mi], bfr[ni], acc[mi][ni], 0, 0, 0);
    __syncthreads();
  }

  const int colb = n0 + wn + fr;
  const int rowb = m0 + wm + (ln >> 4) * 4;
  float cb[4];
  #pragma unroll
  for (int ni = 0; ni < 4; ni++) cb[ni] = bias[colb + ni * 16];
  #pragma unroll
  for (int mi = 0; mi < 4; mi++)
    #pragma unroll
    for (int r = 0; r < 4; r++) {
      const long mr = rowb + mi * 16 + r;
      #pragma unroll
      for (int ni = 0; ni < 4; ni++)
        TPT2[mr * 256 + colb + ni * 16] = f2bf(acc[mi][ni][r] + cb[ni]);
    }
}

// ---------------- fused G GEMM: G[c'][px] = wg · x + b_g -------------------
// M=256 (full) x N=128 px per block, 8 waves. A = wg bf16 via async_ld16;
// B = x f32 via stage_tr (waves 0..3). x read exactly once.
__global__ __launch_bounds__(512, 2)
void gemmG_f(const float* __restrict__ x, const short* __restrict__ wg,
             const float* __restrict__ bg, short* __restrict__ G)
{
  __shared__ __align__(16) short As[256 * 32];   // wg rows, linear
  __shared__ __align__(16) short Bs[128 * 32];   // [px][c] bf16, swizzled
  const int img = blockIdx.y;
  const int n0 = blockIdx.x * 128;               // px
  const float* src = x + (long)img * 512 * 4096;
  const int t = threadIdx.x;
  const int wv = t >> 6, ln = t & 63;
  const int wr = wv >> 1, wc = wv & 1;           // 4 m-waves x 2 n-waves
  const int fr = ln & 15, q8 = (ln >> 4) * 8;
  const int rowA = t >> 2, kc = (t & 3) * 8;

  f32x4 acc[4][4];
  #pragma unroll
  for (int i = 0; i < 4; i++)
    #pragma unroll
    for (int j = 0; j < 4; j++)
      #pragma unroll
      for (int r = 0; r < 4; r++) acc[i][j][r] = 0.f;

  for (int kk = 0; kk < 512; kk += 32) {
    async_ld16(wg + (long)rowA * 512 + kk + kc, As + wv * 512);
    async_ld16(wg + (long)(128 + rowA) * 512 + kk + kc, As + 4096 + wv * 512);
    if (t < 256) stage_tr(src, kk, n0, t, Bs);
    __syncthreads();
    short8 af[4], bfr[4];
    #pragma unroll
    for (int mi = 0; mi < 4; mi++) af[mi] = *(const short8*)&As[(wr * 64 + mi * 16 + fr) * 32 + q8];
    #pragma unroll
    for (int ni = 0; ni < 4; ni++) bfr[ni] = frag_sw(Bs, wc * 64 + ni * 16 + fr, q8);
    #pragma unroll
    for (int mi = 0; mi < 4; mi++)
      #pragma unroll
      for (int ni = 0; ni < 4; ni++)
        acc[mi][ni] = __builtin_amdgcn_mfma_f32_16x16x32_bf16(af[mi], bfr[ni], acc[mi][ni], 0, 0, 0);
    __syncthreads();
  }

  const int colb = n0 + wc * 64 + fr;
  const int rowb = wr * 64 + (ln >> 4) * 4;
  #pragma unroll
  for (int mi = 0; mi < 4; mi++)
    #pragma unroll
    for (int r = 0; r < 4; r++) {
      const int mr = rowb + mi * 16 + r;
      const float badd = bg[mr];
      #pragma unroll
      for (int ni = 0; ni < 4; ni++)
        G[((long)img << 20) + (long)mr * 4096 + colb + ni * 16] = f2bf(acc[mi][ni][r] + badd);
    }
}

// ---------------- scores: E = exp(TT2·PT2^T), fused column partial sums ----
__global__ __launch_bounds__(256)
void scores_k(const short* __restrict__ TT2, const short* __restrict__ PT2,
              short* __restrict__ ST, float* __restrict__ pstats)
{
  __shared__ __align__(16) short As[128 * 32];
  __shared__ __align__(16) short Bs[128 * 32];
  const int bz = blockIdx.z, by = blockIdx.y, bx = blockIdx.x;
  const int t = threadIdx.x;
  const int wv = t >> 6, ln = t & 63;
  const int wm = (wv >> 1) * 64, wn = (wv & 1) * 64;
  const int fr = ln & 15, q8 = (ln >> 4) * 8;
  const int rowA = t >> 2, kc = (t & 3) * 8;

  f32x4 acc[4][4];
  #pragma unroll
  for (int i = 0; i < 4; i++)
    #pragma unroll
    for (int j = 0; j < 4; j++)
      #pragma unroll
      for (int r = 0; r < 4; r++) acc[i][j][r] = 0.f;

  #pragma unroll
  for (int h = 0; h < 2; h++) {
    const short* Aseg = TT2 + ((long)(bz * 4096 + h * 2048 + by * 128)) * 256;
    const short* Bseg = PT2 + ((long)(bz * 4096 + h * 2048 + bx * 128)) * 256;
    for (int kk = 0; kk < 256; kk += 32) {
      #pragma unroll
      for (int s = 0; s < 2; s++) {
        async_ld16(Aseg + (long)(s * 64 + rowA) * 256 + kk + kc, As + (s * 256 + wv * 64) * 8);
        async_ld16(Bseg + (long)(s * 64 + rowA) * 256 + kk + kc, Bs + (s * 256 + wv * 64) * 8);
      }
      __syncthreads();
      short8 af[4], bfr[4];
      #pragma unroll
      for (int mi = 0; mi < 4; mi++) af[mi] = *(const short8*)&As[(wm + mi * 16 + fr) * 32 + q8];
      #pragma unroll
      for (int ni = 0; ni < 4; ni++) bfr[ni] = *(const short8*)&Bs[(wn + ni * 16 + fr) * 32 + q8];
      #pragma unroll
      for (int mi = 0; mi < 4; mi++)
        #pragma unroll
        for (int ni = 0; ni < 4; ni++)
          acc[mi][ni] = __builtin_amdgcn_mfma_f32_16x16x32_bf16(af[mi], bfr[ni], acc[mi][ni], 0, 0, 0);
      __syncthreads();
    }
  }

  const int colb = bx * 128 + wn + fr;
  const int rowb = by * 128 + wm + (ln >> 4) * 4;
  short* base = ST + ((long)bz << 22);
  float ps[4] = {0.f, 0.f, 0.f, 0.f};
  #pragma unroll
  for (int mi = 0; mi < 4; mi++)
    #pragma unroll
    for (int r = 0; r < 4; r++) {
      const long mr = rowb + mi * 16 + r;
      #pragma unroll
      for (int ni = 0; ni < 4; ni++) {
        float e = __expf(acc[mi][ni][r]);
        base[mr * 2048 + colb + ni * 16] = f2bf(e);
        ps[ni] += e;
      }
    }
  #pragma unroll
  for (int ni = 0; ni < 4; ni++) {
    ps[ni] += __shfl_xor(ps[ni], 16);
    ps[ni] += __shfl_xor(ps[ni], 32);
  }
  float* part = (float*)As;
  if (ln < 16) {
    #pragma unroll
    for (int ni = 0; ni < 4; ni++)
      part[(wv >> 1) * 128 + wn + ni * 16 + fr] = ps[ni];
  }
  __syncthreads();
  if (t < 128)
    pstats[((long)(bz * 16 + by)) * 2048 + bx * 128 + t] = part[t] + part[128 + t];
}

// ---------------- reduce 16 partials -> invZ per column --------------------
__global__ __launch_bounds__(256)
void zfinal(const float* __restrict__ pstats, float* __restrict__ invZ)
{
  const int g = blockIdx.x * 256 + threadIdx.x;
  const int b = g >> 11, col = g & 2047;
  float S = 0.f;
  #pragma unroll
  for (int rc = 0; rc < 16; rc++) S += pstats[((long)(b * 16 + rc)) * 2048 + col];
  invZ[g] = 1.f / S;
}

// ---------------- G *= invZ[m] (in place) ----------------------------------
__global__ __launch_bounds__(256)
void g_scale(short* __restrict__ G, const float* __restrict__ invZ)
{
  const long base = ((long)blockIdx.x * 256 + threadIdx.x) * 8;
  const int bz = (int)(base >> 20);
  const int n2 = (int)(base & 4095);
  const float* z = invZ + bz * 2048 + (n2 & 2047);
  short8 v = *(short8*)&G[base];
  f32x4 z0 = *(const f32x4*)z;
  f32x4 z1 = *(const f32x4*)(z + 4);
  #pragma unroll
  for (int j = 0; j < 4; j++) { v[j] = f2bf(bf2f(v[j]) * z0[j]); v[4 + j] = f2bf(bf2f(v[4 + j]) * z1[j]); }
  *(short8*)&G[base] = v;
}

// ---------------- mask GEMM ------------------------------------------------
__global__ __launch_bounds__(256)
void mask_k(const short* __restrict__ Wm20, const short* __restrict__ Wm21,
            const short* __restrict__ OVT, const float* __restrict__ bmask,
            const float* __restrict__ x, float* __restrict__ out)
{
  __shared__ __align__(16) short As[128 * 32];
  __shared__ __align__(16) short Bs[128 * 32];
  const int bz = blockIdx.z;
  const int n0 = blockIdx.x * 128;
  const int m0 = blockIdx.y * 128;
  const short* A = (n0 >= 2048) ? Wm21 : Wm20;
  const short* B = OVT + ((long)bz << 20) + (long)(n0 & 2047) * 512;
  const int t = threadIdx.x;
  const int wv = t >> 6, ln = t & 63;
  const int wm = (wv >> 1) * 64, wn = (wv & 1) * 64;
  const int fr = ln & 15, q8 = (ln >> 4) * 8;
  const int rowA = t >> 2, kc = (t & 3) * 8;

  f32x4 acc[4][4];
  #pragma unroll
  for (int i = 0; i < 4; i++)
    #pragma unroll
    for (int j = 0; j < 4; j++)
      #pragma unroll
      for (int r = 0; r < 4; r++) acc[i][j][r] = 0.f;

  for (int kk = 0; kk < 512; kk += 32) {
    #pragma unroll
    for (int s = 0; s < 2; s++) {
      async_ld16(A + (long)(m0 + s * 64 + rowA) * 512 + kk + kc, As + (s * 256 + wv * 64) * 8);
      async_ld16(B + (long)(s * 64 + rowA) * 512 + kk + kc, Bs + (s * 256 + wv * 64) * 8);
    }
    __syncthreads();
    short8 af[4], bfr[4];
    #pragma unroll
    for (int mi = 0; mi < 4; mi++) af[mi] = *(const short8*)&As[(wm + mi * 16 + fr) * 32 + q8];
    #pragma unroll
    for (int ni = 0; ni < 4; ni++) bfr[ni] = *(const short8*)&Bs[(wn + ni * 16 + fr) * 32 + q8];
    #pragma unroll
    for (int mi = 0; mi < 4; mi++)
      #pragma unroll
      for (int ni = 0; ni < 4; ni++)
        acc[mi][ni] = __builtin_amdgcn_mfma_f32_16x16x32_bf16(af[mi], bfr[ni], acc[mi][ni], 0, 0, 0);
    __syncthreads();
  }

  const int colb = n0 + wn + fr;
  const int rowb = m0 + wm + (ln >> 4) * 4;
  #pragma unroll
  for (int mi = 0; mi < 4; mi++)
    #pragma unroll
    for (int r = 0; r < 4; r++) {
      const int mr = rowb + mi * 16 + r;
      const float badd = bmask[mr];
      const long rbase = ((long)bz * 512 + mr) * 4096;
      #pragma unroll
      for (int ni = 0; ni < 4; ni++) {
        const int cc = colb + ni * 16;
        out[rbase + cc] = acc[mi][ni][r] + badd + x[rbase + cc];
      }
    }
}

// ---------------- weight prep ----------------------------------------------
__global__ __launch_bounds__(256)
void wconv2(const float* w_phi, const float* w_theta, const float* w_g,
            const float* w_mask,
            short* wph, short* wth, short* wg, short* Wm20, short* Wm21)
{
  const int seg = blockIdx.x >> 6;
  const int blk = blockIdx.x & 63;
  const int i0 = blk * 2048 + threadIdx.x * 8;
  if (seg < 3) {
    const float* s = seg == 0 ? w_phi : seg == 1 ? w_theta : w_g;
    short* d = seg == 0 ? wph : seg == 1 ? wth : wg;
    f32x4 a = *(const f32x4*)&s[i0];
    f32x4 b = *(const f32x4*)&s[i0 + 4];
    short8 o;
    #pragma unroll
    for (int j = 0; j < 4; j++) { o[j] = f2bf(a[j]); o[4 + j] = f2bf(b[j]); }
    *(short8*)&d[i0] = o;
  } else {
    const int o = i0 >> 8;
    f32x4 a = *(const f32x4*)&w_mask[i0];
    f32x4 b = *(const f32x4*)&w_mask[i0 + 4];
    short v[8];
    #pragma unroll
    for (int j = 0; j < 4; j++) { v[j] = f2bf(a[j]); v[4 + j] = f2bf(b[j]); }
    short8 a0, a1, b0, b1;
    #pragma unroll
    for (int j = 0; j < 4; j++) {
      a0[2 * j] = v[j];     a0[2 * j + 1] = 0;
      a1[2 * j] = v[4 + j]; a1[2 * j + 1] = 0;
      b0[2 * j] = 0;        b0[2 * j + 1] = v[j];
      b1[2 * j] = 0;        b1[2 * j + 1] = v[4 + j];
    }
    const long base = (long)o * 512 + 2 * (i0 & 255);
    *(short8*)&Wm20[base] = a0; *(short8*)&Wm20[base + 8] = a1;
    *(short8*)&Wm21[base] = b0; *(short8*)&Wm21[base + 8] = b1;
  }
}

// ---------------------------------------------------------------------------
extern "C" void kernel_launch(void* const* d_in, const int* in_sizes, int n_in,
                              void* d_out, int out_size, void* d_ws, size_t ws_size,
                              hipStream_t stream)
{
  (void)in_sizes; (void)n_in; (void)out_size; (void)ws_size;
  const float* x       = (const float*)d_in[0];
  const float* y       = (const float*)d_in[1];
  const float* w_phi   = (const float*)d_in[2];
  const float* b_phi   = (const float*)d_in[3];
  const float* w_theta = (const float*)d_in[4];
  const float* b_theta = (const float*)d_in[5];
  const float* w_g     = (const float*)d_in[6];
  const float* b_g     = (const float*)d_in[7];
  const float* w_mask  = (const float*)d_in[8];
  const float* b_mask  = (const float*)d_in[9];
  float* out = (float*)d_out;

  char* ws = (char*)d_ws;
  const long MB = 1L << 20;
  short* wph  = (short*)(ws + 0);
  short* wth  = (short*)(ws + 256 * 1024);
  short* wg   = (short*)(ws + 512 * 1024);
  short* Wm20 = (short*)(ws + 768 * 1024);
  short* Wm21 = (short*)(ws + 1280 * 1024);
  short* TPT2 = (short*)(ws + 66 * MB);   // [65536][256], 32MB
  short* G    = (short*)(ws + 98 * MB);   // [8][256][4096], 16MB
  short* ST   = (short*)(ws + 2 * MB);    // [8][2048][2048] E, 64MB
  float* pstats = (float*)(ws + 114 * MB);
  float* invZ   = (float*)(ws + 115 * MB);
  short* OVT  = (short*)(ws + 66 * MB);   // [8][2048][512], 16MB (over TPT2)

  dim3 blk(256, 1, 1);
  dim3 blk8(512, 1, 1);

  wconv2<<<dim3(256, 1, 1), blk, 0, stream>>>(w_phi, w_theta, w_g, w_mask,
                                              wph, wth, wg, Wm20, Wm21);

  conv_ptf<<<dim3(2, 512, 1), blk, 0, stream>>>(x, y, wth, wph, b_theta, b_phi, TPT2);

  gemmG_f<<<dim3(32, 8, 1), blk8, 0, stream>>>(x, wg, b_g, G);

  scores_k<<<dim3(16, 16, 8), blk, 0, stream>>>(TPT2, TPT2 + 32768L * 256, ST, pstats);
  zfinal<<<dim3(64, 1, 1), blk, 0, stream>>>(pstats, invZ);
  g_scale<<<dim3(4096, 1, 1), blk, 0, stream>>>(G, invZ);

  ov_k<<<dim3(512, 1, 1), blk8, 0, stream>>>(ST, G, OVT);

  mask_k<<<dim3(32, 4, 8), blk, 0, stream>>>(Wm20, Wm21, OVT, b_mask, x, out);
}

// Round 5
// 358.237 us; speedup vs baseline: 1.1497x; 1.0483x over previous
//
#include <hip/hip_runtime.h>
#include <hip/hip_bf16.h>

// Non-local block, B=8 C=512 H=W=64, IC=256, N2=HW=4096, N=2048 (folded).
//
// Round-9: conv_ptf/gemmG_f v2 — double-buffered one-barrier K-loop.
// Full IC=256 per block (each px-slab staged ONCE, was twice), role-split
// staging: waves 0-3 load f32 img tile to regs (write LDS after MFMA),
// waves 4-7 async global_load_lds the next weight tile. Loads issued BEFORE
// the current step's MFMA -> latency hides under compute (T14/T3-lite).
// Rest identical to round 8.

typedef __attribute__((ext_vector_type(8))) short short8;
typedef __attribute__((ext_vector_type(4))) short short4v;
typedef __attribute__((ext_vector_type(4))) float f32x4;

__device__ __forceinline__ short f2bf(float f) {
  union { __hip_bfloat16 h; short s; } u; u.h = __float2bfloat16(f); return u.s;
}
__device__ __forceinline__ float bf2f(short s) {
  union { short s; __hip_bfloat16 h; } u; u.s = s; return __bfloat162float(u.h);
}

__device__ __forceinline__ void async_ld16(const void* g, void* l) {
  __builtin_amdgcn_global_load_lds(
      (const __attribute__((address_space(1))) unsigned int*)(unsigned long long)g,
      (__attribute__((address_space(3))) unsigned int*)(unsigned int)(unsigned long long)l,
      16, 0, 0);
}

// swizzled b128 fragment read from a transposed img tile ([px][32c], 16B-unit
// XOR swizzle u ^= (px>>2)&3)
__device__ __forceinline__ short8 frag_sw(const short* Ds, int row, int q8)
{
  return *(const short8*)&Ds[row * 32 + (((q8 >> 3) ^ ((row >> 2) & 3)) << 3)];
}

// ---------------- OV GEMM with XCD-locality swizzle ------------------------
__global__ __launch_bounds__(512, 4)
void ov_k(const short* __restrict__ Eg, const short* __restrict__ Gg,
          short* __restrict__ Cg)
{
  const int L = blockIdx.x;
  const int xcd = L & 7, k = L >> 3;
  const int slab = xcd + ((k >> 2) << 3);   // 0..127
  const int bz = slab >> 4, by = slab & 15, bx = k & 3;

  __shared__ __align__(16) short As[128 * 32];
  __shared__ __align__(16) short Bs[128 * 32];
  const short* A = Eg + ((long)bz << 22);
  const short* B = Gg + ((long)bz << 20);
  const int m0 = by * 128;
  const int n0 = bx * 128;
  const int t = threadIdx.x;
  const int wv = t >> 6, ln = t & 63;
  const int wr = wv >> 1, wc = wv & 1;
  const int fr = ln & 15, q8 = (ln >> 4) * 8;
  const int rowA = t >> 2, kc = (t & 3) * 8;

  f32x4 acc[2][4];
  #pragma unroll
  for (int i = 0; i < 2; i++)
    #pragma unroll
    for (int j = 0; j < 4; j++)
      #pragma unroll
      for (int r = 0; r < 4; r++) acc[i][j][r] = 0.f;

  for (int kk = 0; kk < 2048; kk += 32) {
    async_ld16(A + (long)(m0 + rowA) * 2048 + kk + kc, As + wv * 512);
    async_ld16(B + (long)(n0 + rowA) * 2048 + kk + kc, Bs + wv * 512);
    __syncthreads();
    short8 af[2], bfr[4];
    #pragma unroll
    for (int mi = 0; mi < 2; mi++) af[mi] = *(const short8*)&As[(wr * 32 + mi * 16 + fr) * 32 + q8];
    #pragma unroll
    for (int ni = 0; ni < 4; ni++) bfr[ni] = *(const short8*)&Bs[(wc * 64 + ni * 16 + fr) * 32 + q8];
    #pragma unroll
    for (int mi = 0; mi < 2; mi++)
      #pragma unroll
      for (int ni = 0; ni < 4; ni++)
        acc[mi][ni] = __builtin_amdgcn_mfma_f32_16x16x32_bf16(af[mi], bfr[ni], acc[mi][ni], 0, 0, 0);
    __syncthreads();
  }

  const int colb = n0 + wc * 64 + fr;
  const int rowb = m0 + wr * 32 + (ln >> 4) * 4;
  #pragma unroll
  for (int mi = 0; mi < 2; mi++)
    #pragma unroll
    for (int r = 0; r < 4; r++) {
      const int mr = rowb + mi * 16 + r;
      #pragma unroll
      for (int ni = 0; ni < 4; ni++)
        Cg[((long)bz << 20) + (long)mr * 512 + colb + ni * 16] = f2bf(acc[mi][ni][r]);
    }
}

// ---------------- fused theta/phi conv v2: dbuf, full IC -------------------
// TPT2[m][ic] = sum_c img[c][px]*W[ic][c] + b.  512 blocks: slab<256 theta(x),
// else phi(y). Per block: 128 px x 256 ic, K=512 in 16 steps of 32.
// waves 0-3: img f32->reg (issue early) -> cvt+swizzled ds_write (late).
// waves 4-7: weight async_ld16 into next buffer.  One barrier per step.
__global__ __launch_bounds__(512, 4)
void conv_ptf(const float* __restrict__ x, const float* __restrict__ y,
              const short* __restrict__ wth, const short* __restrict__ wph,
              const float* __restrict__ bth, const float* __restrict__ bph,
              short* __restrict__ TPT2)
{
  __shared__ __align__(16) short As[2][128 * 32];   // img [px][32c], swizzled
  __shared__ __align__(16) short Bs[2][256 * 32];   // weights, linear
  const int slab = blockIdx.x;                      // 0..511
  const bool isphi = slab >= 256;
  const int s2 = slab & 255;
  const float* src = (isphi ? y : x) + (long)(s2 >> 5) * (512L * 4096);
  const int px0 = (s2 & 31) * 128;
  const long m0 = (long)slab * 128;
  const short* W = isphi ? wph : wth;
  const float* bias = isphi ? bph : bth;
  const int t = threadIdx.x;
  const int wv = t >> 6, ln = t & 63;
  const int wpx = wv >> 2, wic = wv & 3;
  const int fr = ln & 15, q8 = (ln >> 4) * 8;
  const int g4 = (t >> 5) * 4, p4 = (t & 31) * 4;   // img stager coords
  const int w2 = wv - 4;                            // weight stager wave

  f32x4 acc[4][4];
  #pragma unroll
  for (int i = 0; i < 4; i++)
    #pragma unroll
    for (int j = 0; j < 4; j++)
      #pragma unroll
      for (int r = 0; r < 4; r++) acc[i][j][r] = 0.f;

  // ---- prologue: fill buffer 0 (k-step 0)
  if (t >= 256) {
    #pragma unroll
    for (int j = 0; j < 4; j++)
      async_ld16(W + (long)(w2 * 64 + j * 16 + (ln >> 2)) * 512 + (ln & 3) * 8,
                 &Bs[0][(w2 * 64 + j * 16) * 32]);
  } else {
    f32x4 r[4];
    #pragma unroll
    for (int i = 0; i < 4; i++)
      r[i] = *(const f32x4*)&src[(long)(g4 + i) * 4096 + px0 + p4];
    #pragma unroll
    for (int j = 0; j < 4; j++) {
      short4v w;
      w[0] = f2bf(r[0][j]); w[1] = f2bf(r[1][j]); w[2] = f2bf(r[2][j]); w[3] = f2bf(r[3][j]);
      const int px = p4 + j;
      const int u = (g4 >> 3) ^ ((px >> 2) & 3);
      *(short4v*)&As[0][px * 32 + u * 8 + (g4 & 4)] = w;
    }
  }
  __syncthreads();

  // ---- main loop: 15 iterations, compute k-1 while staging k
  for (int k = 1; k < 16; k++) {
    const int cur = (k - 1) & 1, nxt = k & 1;
    f32x4 r[4];
    if (t >= 256) {
      #pragma unroll
      for (int j = 0; j < 4; j++)
        async_ld16(W + (long)(w2 * 64 + j * 16 + (ln >> 2)) * 512 + k * 32 + (ln & 3) * 8,
                   &Bs[nxt][(w2 * 64 + j * 16) * 32]);
    } else {
      #pragma unroll
      for (int i = 0; i < 4; i++)
        r[i] = *(const f32x4*)&src[(long)(k * 32 + g4 + i) * 4096 + px0 + p4];
    }
    short8 af[4], bfv[4];
    #pragma unroll
    for (int mi = 0; mi < 4; mi++) af[mi] = frag_sw(&As[cur][0], wpx * 64 + mi * 16 + fr, q8);
    #pragma unroll
    for (int ni = 0; ni < 4; ni++) bfv[ni] = *(const short8*)&Bs[cur][(wic * 64 + ni * 16 + fr) * 32 + q8];
    #pragma unroll
    for (int mi = 0; mi < 4; mi++)
      #pragma unroll
      for (int ni = 0; ni < 4; ni++)
        acc[mi][ni] = __builtin_amdgcn_mfma_f32_16x16x32_bf16(af[mi], bfv[ni], acc[mi][ni], 0, 0, 0);
    if (t < 256) {
      #pragma unroll
      for (int j = 0; j < 4; j++) {
        short4v w;
        w[0] = f2bf(r[0][j]); w[1] = f2bf(r[1][j]); w[2] = f2bf(r[2][j]); w[3] = f2bf(r[3][j]);
        const int px = p4 + j;
        const int u = (g4 >> 3) ^ ((px >> 2) & 3);
        *(short4v*)&As[nxt][px * 32 + u * 8 + (g4 & 4)] = w;
      }
    }
    __syncthreads();
  }

  // ---- final k-step (buffer 1)
  {
    short8 af[4], bfv[4];
    #pragma unroll
    for (int mi = 0; mi < 4; mi++) af[mi] = frag_sw(&As[1][0], wpx * 64 + mi * 16 + fr, q8);
    #pragma unroll
    for (int ni = 0; ni < 4; ni++) bfv[ni] = *(const short8*)&Bs[1][(wic * 64 + ni * 16 + fr) * 32 + q8];
    #pragma unroll
    for (int mi = 0; mi < 4; mi++)
      #pragma unroll
      for (int ni = 0; ni < 4; ni++)
        acc[mi][ni] = __builtin_amdgcn_mfma_f32_16x16x32_bf16(af[mi], bfv[ni], acc[mi][ni], 0, 0, 0);
  }

  const int colic = wic * 64 + fr;
  float cb[4];
  #pragma unroll
  for (int ni = 0; ni < 4; ni++) cb[ni] = bias[colic + ni * 16];
  #pragma unroll
  for (int mi = 0; mi < 4; mi++)
    #pragma unroll
    for (int r = 0; r < 4; r++) {
      const long m = m0 + wpx * 64 + mi * 16 + (ln >> 4) * 4 + r;
      #pragma unroll
      for (int ni = 0; ni < 4; ni++)
        TPT2[m * 256 + colic + ni * 16] = f2bf(acc[mi][ni][r] + cb[ni]);
    }
}

// ---------------- fused G GEMM v2: dbuf, same schedule ---------------------
// G[ic'][px] = wg · x + b_g.  M=256 wg rows (waves 4-7 stage, linear) x
// N=128 px (waves 0-3 stage f32->reg->swizzled LDS). 256 blocks.
__global__ __launch_bounds__(512, 4)
void gemmG_f(const float* __restrict__ x, const short* __restrict__ wg,
             const float* __restrict__ bg, short* __restrict__ G)
{
  __shared__ __align__(16) short As[2][256 * 32];   // wg, linear
  __shared__ __align__(16) short Bs[2][128 * 32];   // img [px][32c], swizzled
  const int img = blockIdx.y;
  const int n0 = blockIdx.x * 128;
  const float* src = x + (long)img * 512 * 4096;
  const int t = threadIdx.x;
  const int wv = t >> 6, ln = t & 63;
  const int wr = wv >> 1, wc = wv & 1;
  const int fr = ln & 15, q8 = (ln >> 4) * 8;
  const int g4 = (t >> 5) * 4, p4 = (t & 31) * 4;
  const int w2 = wv - 4;

  f32x4 acc[4][4];
  #pragma unroll
  for (int i = 0; i < 4; i++)
    #pragma unroll
    for (int j = 0; j < 4; j++)
      #pragma unroll
      for (int r = 0; r < 4; r++) acc[i][j][r] = 0.f;

  if (t >= 256) {
    #pragma unroll
    for (int j = 0; j < 4; j++)
      async_ld16(wg + (long)(w2 * 64 + j * 16 + (ln >> 2)) * 512 + (ln & 3) * 8,
                 &As[0][(w2 * 64 + j * 16) * 32]);
  } else {
    f32x4 r[4];
    #pragma unroll
    for (int i = 0; i < 4; i++)
      r[i] = *(const f32x4*)&src[(long)(g4 + i) * 4096 + n0 + p4];
    #pragma unroll
    for (int j = 0; j < 4; j++) {
      short4v w;
      w[0] = f2bf(r[0][j]); w[1] = f2bf(r[1][j]); w[2] = f2bf(r[2][j]); w[3] = f2bf(r[3][j]);
      const int px = p4 + j;
      const int u = (g4 >> 3) ^ ((px >> 2) & 3);
      *(short4v*)&Bs[0][px * 32 + u * 8 + (g4 & 4)] = w;
    }
  }
  __syncthreads();

  for (int k = 1; k < 16; k++) {
    const int cur = (k - 1) & 1, nxt = k & 1;
    f32x4 r[4];
    if (t >= 256) {
      #pragma unroll
      for (int j = 0; j < 4; j++)
        async_ld16(wg + (long)(w2 * 64 + j * 16 + (ln >> 2)) * 512 + k * 32 + (ln & 3) * 8,
                   &As[nxt][(w2 * 64 + j * 16) * 32]);
    } else {
      #pragma unroll
      for (int i = 0; i < 4; i++)
        r[i] = *(const f32x4*)&src[(long)(k * 32 + g4 + i) * 4096 + n0 + p4];
    }
    short8 af[4], bfv[4];
    #pragma unroll
    for (int mi = 0; mi < 4; mi++) af[mi] = *(const short8*)&As[cur][(wr * 64 + mi * 16 + fr) * 32 + q8];
    #pragma unroll
    for (int ni = 0; ni < 4; ni++) bfv[ni] = frag_sw(&Bs[cur][0], wc * 64 + ni * 16 + fr, q8);
    #pragma unroll
    for (int mi = 0; mi < 4; mi++)
      #pragma unroll
      for (int ni = 0; ni < 4; ni++)
        acc[mi][ni] = __builtin_amdgcn_mfma_f32_16x16x32_bf16(af[mi], bfv[ni], acc[mi][ni], 0, 0, 0);
    if (t < 256) {
      #pragma unroll
      for (int j = 0; j < 4; j++) {
        short4v w;
        w[0] = f2bf(r[0][j]); w[1] = f2bf(r[1][j]); w[2] = f2bf(r[2][j]); w[3] = f2bf(r[3][j]);
        const int px = p4 + j;
        const int u = (g4 >> 3) ^ ((px >> 2) & 3);
        *(short4v*)&Bs[nxt][px * 32 + u * 8 + (g4 & 4)] = w;
      }
    }
    __syncthreads();
  }

  {
    short8 af[4], bfv[4];
    #pragma unroll
    for (int mi = 0; mi < 4; mi++) af[mi] = *(const short8*)&As[1][(wr * 64 + mi * 16 + fr) * 32 + q8];
    #pragma unroll
    for (int ni = 0; ni < 4; ni++) bfv[ni] = frag_sw(&Bs[1][0], wc * 64 + ni * 16 + fr, q8);
    #pragma unroll
    for (int mi = 0; mi < 4; mi++)
      #pragma unroll
      for (int ni = 0; ni < 4; ni++)
        acc[mi][ni] = __builtin_amdgcn_mfma_f32_16x16x32_bf16(af[mi], bfv[ni], acc[mi][ni], 0, 0, 0);
  }

  const int colb = n0 + wc * 64 + fr;
  const int rowb = wr * 64 + (ln >> 4) * 4;
  #pragma unroll
  for (int mi = 0; mi < 4; mi++)
    #pragma unroll
    for (int r = 0; r < 4; r++) {
      const int mr = rowb + mi * 16 + r;
      const float badd = bg[mr];
      #pragma unroll
      for (int ni = 0; ni < 4; ni++)
        G[((long)img << 20) + (long)mr * 4096 + colb + ni * 16] = f2bf(acc[mi][ni][r] + badd);
    }
}

// ---------------- scores: E = exp(TT2·PT2^T), fused column partial sums ----
__global__ __launch_bounds__(256)
void scores_k(const short* __restrict__ TT2, const short* __restrict__ PT2,
              short* __restrict__ ST, float* __restrict__ pstats)
{
  __shared__ __align__(16) short As[128 * 32];
  __shared__ __align__(16) short Bs[128 * 32];
  const int bz = blockIdx.z, by = blockIdx.y, bx = blockIdx.x;
  const int t = threadIdx.x;
  const int wv = t >> 6, ln = t & 63;
  const int wm = (wv >> 1) * 64, wn = (wv & 1) * 64;
  const int fr = ln & 15, q8 = (ln >> 4) * 8;
  const int rowA = t >> 2, kc = (t & 3) * 8;

  f32x4 acc[4][4];
  #pragma unroll
  for (int i = 0; i < 4; i++)
    #pragma unroll
    for (int j = 0; j < 4; j++)
      #pragma unroll
      for (int r = 0; r < 4; r++) acc[i][j][r] = 0.f;

  #pragma unroll
  for (int h = 0; h < 2; h++) {
    const short* Aseg = TT2 + ((long)(bz * 4096 + h * 2048 + by * 128)) * 256;
    const short* Bseg = PT2 + ((long)(bz * 4096 + h * 2048 + bx * 128)) * 256;
    for (int kk = 0; kk < 256; kk += 32) {
      #pragma unroll
      for (int s = 0; s < 2; s++) {
        async_ld16(Aseg + (long)(s * 64 + rowA) * 256 + kk + kc, As + (s * 256 + wv * 64) * 8);
        async_ld16(Bseg + (long)(s * 64 + rowA) * 256 + kk + kc, Bs + (s * 256 + wv * 64) * 8);
      }
      __syncthreads();
      short8 af[4], bfr[4];
      #pragma unroll
      for (int mi = 0; mi < 4; mi++) af[mi] = *(const short8*)&As[(wm + mi * 16 + fr) * 32 + q8];
      #pragma unroll
      for (int ni = 0; ni < 4; ni++) bfr[ni] = *(const short8*)&Bs[(wn + ni * 16 + fr) * 32 + q8];
      #pragma unroll
      for (int mi = 0; mi < 4; mi++)
        #pragma unroll
        for (int ni = 0; ni < 4; ni++)
          acc[mi][ni] = __builtin_amdgcn_mfma_f32_16x16x32_bf16(af[mi], bfr[ni], acc[mi][ni], 0, 0, 0);
      __syncthreads();
    }
  }

  const int colb = bx * 128 + wn + fr;
  const int rowb = by * 128 + wm + (ln >> 4) * 4;
  short* base = ST + ((long)bz << 22);
  float ps[4] = {0.f, 0.f, 0.f, 0.f};
  #pragma unroll
  for (int mi = 0; mi < 4; mi++)
    #pragma unroll
    for (int r = 0; r < 4; r++) {
      const long mr = rowb + mi * 16 + r;
      #pragma unroll
      for (int ni = 0; ni < 4; ni++) {
        float e = __expf(acc[mi][ni][r]);
        base[mr * 2048 + colb + ni * 16] = f2bf(e);
        ps[ni] += e;
      }
    }
  #pragma unroll
  for (int ni = 0; ni < 4; ni++) {
    ps[ni] += __shfl_xor(ps[ni], 16);
    ps[ni] += __shfl_xor(ps[ni], 32);
  }
  float* part = (float*)As;
  if (ln < 16) {
    #pragma unroll
    for (int ni = 0; ni < 4; ni++)
      part[(wv >> 1) * 128 + wn + ni * 16 + fr] = ps[ni];
  }
  __syncthreads();
  if (t < 128)
    pstats[((long)(bz * 16 + by)) * 2048 + bx * 128 + t] = part[t] + part[128 + t];
}

// ---------------- reduce 16 partials -> invZ per column --------------------
__global__ __launch_bounds__(256)
void zfinal(const float* __restrict__ pstats, float* __restrict__ invZ)
{
  const int g = blockIdx.x * 256 + threadIdx.x;
  const int b = g >> 11, col = g & 2047;
  float S = 0.f;
  #pragma unroll
  for (int rc = 0; rc < 16; rc++) S += pstats[((long)(b * 16 + rc)) * 2048 + col];
  invZ[g] = 1.f / S;
}

// ---------------- G *= invZ[m] (in place) ----------------------------------
__global__ __launch_bounds__(256)
void g_scale(short* __restrict__ G, const float* __restrict__ invZ)
{
  const long base = ((long)blockIdx.x * 256 + threadIdx.x) * 8;
  const int bz = (int)(base >> 20);
  const int n2 = (int)(base & 4095);
  const float* z = invZ + bz * 2048 + (n2 & 2047);
  short8 v = *(short8*)&G[base];
  f32x4 z0 = *(const f32x4*)z;
  f32x4 z1 = *(const f32x4*)(z + 4);
  #pragma unroll
  for (int j = 0; j < 4; j++) { v[j] = f2bf(bf2f(v[j]) * z0[j]); v[4 + j] = f2bf(bf2f(v[4 + j]) * z1[j]); }
  *(short8*)&G[base] = v;
}

// ---------------- mask GEMM ------------------------------------------------
__global__ __launch_bounds__(256)
void mask_k(const short* __restrict__ Wm20, const short* __restrict__ Wm21,
            const short* __restrict__ OVT, const float* __restrict__ bmask,
            const float* __restrict__ x, float* __restrict__ out)
{
  __shared__ __align__(16) short As[128 * 32];
  __shared__ __align__(16) short Bs[128 * 32];
  const int bz = blockIdx.z;
  const int n0 = blockIdx.x * 128;
  const int m0 = blockIdx.y * 128;
  const short* A = (n0 >= 2048) ? Wm21 : Wm20;
  const short* B = OVT + ((long)bz << 20) + (long)(n0 & 2047) * 512;
  const int t = threadIdx.x;
  const int wv = t >> 6, ln = t & 63;
  const int wm = (wv >> 1) * 64, wn = (wv & 1) * 64;
  const int fr = ln & 15, q8 = (ln >> 4) * 8;
  const int rowA = t >> 2, kc = (t & 3) * 8;

  f32x4 acc[4][4];
  #pragma unroll
  for (int i = 0; i < 4; i++)
    #pragma unroll
    for (int j = 0; j < 4; j++)
      #pragma unroll
      for (int r = 0; r < 4; r++) acc[i][j][r] = 0.f;

  for (int kk = 0; kk < 512; kk += 32) {
    #pragma unroll
    for (int s = 0; s < 2; s++) {
      async_ld16(A + (long)(m0 + s * 64 + rowA) * 512 + kk + kc, As + (s * 256 + wv * 64) * 8);
      async_ld16(B + (long)(s * 64 + rowA) * 512 + kk + kc, Bs + (s * 256 + wv * 64) * 8);
    }
    __syncthreads();
    short8 af[4], bfr[4];
    #pragma unroll
    for (int mi = 0; mi < 4; mi++) af[mi] = *(const short8*)&As[(wm + mi * 16 + fr) * 32 + q8];
    #pragma unroll
    for (int ni = 0; ni < 4; ni++) bfr[ni] = *(const short8*)&Bs[(wn + ni * 16 + fr) * 32 + q8];
    #pragma unroll
    for (int mi = 0; mi < 4; mi++)
      #pragma unroll
      for (int ni = 0; ni < 4; ni++)
        acc[mi][ni] = __builtin_amdgcn_mfma_f32_16x16x32_bf16(af[mi], bfr[ni], acc[mi][ni], 0, 0, 0);
    __syncthreads();
  }

  const int colb = n0 + wn + fr;
  const int rowb = m0 + wm + (ln >> 4) * 4;
  #pragma unroll
  for (int mi = 0; mi < 4; mi++)
    #pragma unroll
    for (int r = 0; r < 4; r++) {
      const int mr = rowb + mi * 16 + r;
      const float badd = bmask[mr];
      const long rbase = ((long)bz * 512 + mr) * 4096;
      #pragma unroll
      for (int ni = 0; ni < 4; ni++) {
        const int cc = colb + ni * 16;
        out[rbase + cc] = acc[mi][ni][r] + badd + x[rbase + cc];
      }
    }
}

// ---------------- weight prep ----------------------------------------------
__global__ __launch_bounds__(256)
void wconv2(const float* w_phi, const float* w_theta, const float* w_g,
            const float* w_mask,
            short* wph, short* wth, short* wg, short* Wm20, short* Wm21)
{
  const int seg = blockIdx.x >> 6;
  const int blk = blockIdx.x & 63;
  const int i0 = blk * 2048 + threadIdx.x * 8;
  if (seg < 3) {
    const float* s = seg == 0 ? w_phi : seg == 1 ? w_theta : w_g;
    short* d = seg == 0 ? wph : seg == 1 ? wth : wg;
    f32x4 a = *(const f32x4*)&s[i0];
    f32x4 b = *(const f32x4*)&s[i0 + 4];
    short8 o;
    #pragma unroll
    for (int j = 0; j < 4; j++) { o[j] = f2bf(a[j]); o[4 + j] = f2bf(b[j]); }
    *(short8*)&d[i0] = o;
  } else {
    const int o = i0 >> 8;
    f32x4 a = *(const f32x4*)&w_mask[i0];
    f32x4 b = *(const f32x4*)&w_mask[i0 + 4];
    short v[8];
    #pragma unroll
    for (int j = 0; j < 4; j++) { v[j] = f2bf(a[j]); v[4 + j] = f2bf(b[j]); }
    short8 a0, a1, b0, b1;
    #pragma unroll
    for (int j = 0; j < 4; j++) {
      a0[2 * j] = v[j];     a0[2 * j + 1] = 0;
      a1[2 * j] = v[4 + j]; a1[2 * j + 1] = 0;
      b0[2 * j] = 0;        b0[2 * j + 1] = v[j];
      b1[2 * j] = 0;        b1[2 * j + 1] = v[4 + j];
    }
    const long base = (long)o * 512 + 2 * (i0 & 255);
    *(short8*)&Wm20[base] = a0; *(short8*)&Wm20[base + 8] = a1;
    *(short8*)&Wm21[base] = b0; *(short8*)&Wm21[base + 8] = b1;
  }
}

// ---------------------------------------------------------------------------
extern "C" void kernel_launch(void* const* d_in, const int* in_sizes, int n_in,
                              void* d_out, int out_size, void* d_ws, size_t ws_size,
                              hipStream_t stream)
{
  (void)in_sizes; (void)n_in; (void)out_size; (void)ws_size;
  const float* x       = (const float*)d_in[0];
  const float* y       = (const float*)d_in[1];
  const float* w_phi   = (const float*)d_in[2];
  const float* b_phi   = (const float*)d_in[3];
  const float* w_theta = (const float*)d_in[4];
  const float* b_theta = (const float*)d_in[5];
  const float* w_g     = (const float*)d_in[6];
  const float* b_g     = (const float*)d_in[7];
  const float* w_mask  = (const float*)d_in[8];
  const float* b_mask  = (const float*)d_in[9];
  float* out = (float*)d_out;

  char* ws = (char*)d_ws;
  const long MB = 1L << 20;
  short* wph  = (short*)(ws + 0);
  short* wth  = (short*)(ws + 256 * 1024);
  short* wg   = (short*)(ws + 512 * 1024);
  short* Wm20 = (short*)(ws + 768 * 1024);
  short* Wm21 = (short*)(ws + 1280 * 1024);
  short* TPT2 = (short*)(ws + 66 * MB);   // [65536][256], 32MB
  short* G    = (short*)(ws + 98 * MB);   // [8][256][4096], 16MB
  short* ST   = (short*)(ws + 2 * MB);    // [8][2048][2048] E, 64MB
  float* pstats = (float*)(ws + 114 * MB);
  float* invZ   = (float*)(ws + 115 * MB);
  short* OVT  = (short*)(ws + 66 * MB);   // [8][2048][512], 16MB (over TPT2)

  dim3 blk(256, 1, 1);
  dim3 blk8(512, 1, 1);

  wconv2<<<dim3(256, 1, 1), blk, 0, stream>>>(w_phi, w_theta, w_g, w_mask,
                                              wph, wth, wg, Wm20, Wm21);

  conv_ptf<<<dim3(512, 1, 1), blk8, 0, stream>>>(x, y, wth, wph, b_theta, b_phi, TPT2);

  gemmG_f<<<dim3(32, 8, 1), blk8, 0, stream>>>(x, wg, b_g, G);

  scores_k<<<dim3(16, 16, 8), blk, 0, stream>>>(TPT2, TPT2 + 32768L * 256, ST, pstats);
  zfinal<<<dim3(64, 1, 1), blk, 0, stream>>>(pstats, invZ);
  g_scale<<<dim3(4096, 1, 1), blk, 0, stream>>>(G, invZ);

  ov_k<<<dim3(512, 1, 1), blk8, 0, stream>>>(ST, G, OVT);

  mask_k<<<dim3(32, 4, 8), blk, 0, stream>>>(Wm20, Wm21, OVT, b_mask, x, out);
}